// Round 8
// baseline (6473.599 us; speedup 1.0000x reference)
//
#include <hip/hip_runtime.h>
#include <stdint.h>

typedef __attribute__((ext_vector_type(4))) float f32x4;

constexpr float QK_SCALE = 0.08838834764831845f;  // 128^-0.5

// ===========================================================================
// All-fp32 pipeline (bf16 numerically forbidden: 8-step recursion amplifies
// per-step noise ~1e3-1e4; verified r3-r5). Graph identical to verified r3:
//   proj GEMM -> seq attention (+fused gate) -> memory GEMM -> out.
// Stack-memory collapse (verified r3): all K slots identical -> uniform
// memory attention -> Mq/Mk unused; read = PSUM * (Mm @ Mv_full).
// r7 lesson (measured): batch = bid&7 "XCD-affine" mapping thrashed L2
// (FETCH 69->750 MB, attn 315->640us). Consecutive-block = same-batch
// mapping restored; swizzled LDS + 8-wave split-K + fused gate kept.
// ===========================================================================

__global__ void k_init32(const float* __restrict__ xr, const float* __restrict__ xi,
                         float* __restrict__ Z, float* __restrict__ Mm,
                         float* __restrict__ PSUM){
  for (int i = blockIdx.x*blockDim.x + threadIdx.x; i < 8192*256; i += gridDim.x*blockDim.x){
    int n = i >> 8, d = i & 255;
    Z[i]  = (d < 128) ? xr[n*128 + d] : xi[n*128 + d - 128];
    Mm[i] = 0.f;
    if (i < 8192) PSUM[i] = 1.f;
  }
}

// ---------------- tiled fp32 GEMM (unchanged from verified r6) --------------
template<int EPI>
__launch_bounds__(256, 2)
__global__ void k_gemm32(const float* __restrict__ A, int nb,
                         const float* __restrict__ W0r, const float* __restrict__ W0i,
                         const float* __restrict__ W1r, const float* __restrict__ W1i,
                         const float* __restrict__ W2r, const float* __restrict__ W2i,
                         float* __restrict__ C, const float* __restrict__ PSUM,
                         const float* __restrict__ bias){
  __shared__ float As[32][132];   // [k][m], padded
  __shared__ float Bs[32][132];   // [k][n], padded
  const int bx = blockIdx.x % nb, by = blockIdx.x / nb;
  const int m0 = by << 7, n0 = bx << 7;
  const int tid = threadIdx.x;
  const int tx = tid & 15, ty = tid >> 4;
  const float* Wr = W0r; const float* Wi = W0i;
  if constexpr (EPI == 0){
    int sec = n0 >> 8;
    Wr = (sec == 0) ? W0r : (sec == 1) ? W1r : W2r;
    Wi = (sec == 0) ? W0i : (sec == 1) ? W1i : W2i;
  }
  const int hn = (n0 >> 7) & 1;
  float acc[8][8];
  #pragma unroll
  for (int i = 0; i < 8; ++i)
    #pragma unroll
    for (int j = 0; j < 8; ++j) acc[i][j] = 0.f;

  for (int kt = 0; kt < 8; ++kt){
    if (kt) __syncthreads();
    #pragma unroll
    for (int i = 0; i < 4; ++i){               // A tile: transpose-scatter
      int c = i*256 + tid;
      int row = c >> 3, k4 = c & 7;
      f32x4 v = *(const f32x4*)&A[(size_t)(m0 + row)*256 + kt*32 + k4*4];
      As[k4*4+0][row] = v.x; As[k4*4+1][row] = v.y;
      As[k4*4+2][row] = v.z; As[k4*4+3][row] = v.w;
    }
    #pragma unroll
    for (int i = 0; i < 4; ++i){               // B tile: on-the-fly Wfull
      int c = i*256 + tid;
      int k = c >> 5, n4 = c & 31;
      int gk = kt*32 + k;
      f32x4 v;
      if constexpr (EPI == 2){
        v = *(const f32x4*)&W0r[(size_t)gk*128 + n4*4];
      } else {
        int hk = gk >> 7, kk = gk & 127;
        const float* src = ((hk ^ hn) == 0) ? Wr : Wi;
        v = *(const f32x4*)&src[(size_t)kk*128 + n4*4];
        if (hk == 1 && hn == 0){ v.x = -v.x; v.y = -v.y; v.z = -v.z; v.w = -v.w; }
      }
      *(f32x4*)&Bs[k][n4*4] = v;
    }
    __syncthreads();
    #pragma unroll 8
    for (int k = 0; k < 32; ++k){
      float a[8], b[8];
      *(f32x4*)&a[0] = *(const f32x4*)&As[k][ty*8];
      *(f32x4*)&a[4] = *(const f32x4*)&As[k][ty*8 + 4];
      *(f32x4*)&b[0] = *(const f32x4*)&Bs[k][tx*8];
      *(f32x4*)&b[4] = *(const f32x4*)&Bs[k][tx*8 + 4];
      #pragma unroll
      for (int i = 0; i < 8; ++i)
        #pragma unroll
        for (int j = 0; j < 8; ++j) acc[i][j] += a[i]*b[j];
    }
  }
  #pragma unroll
  for (int i = 0; i < 8; ++i){
    const int row = m0 + ty*8 + i;
    const int col = n0 + tx*8;
    if constexpr (EPI == 0){
      *(f32x4*)&C[(size_t)row*768 + col]     = *(const f32x4*)&acc[i][0];
      *(f32x4*)&C[(size_t)row*768 + col + 4] = *(const f32x4*)&acc[i][4];
    } else if constexpr (EPI == 1){
      const float s = 0.1f * PSUM[row];
      f32x4 z0 = *(const f32x4*)&C[(size_t)row*256 + col];
      f32x4 z1 = *(const f32x4*)&C[(size_t)row*256 + col + 4];
      z0.x += s*acc[i][0]; z0.y += s*acc[i][1]; z0.z += s*acc[i][2]; z0.w += s*acc[i][3];
      z1.x += s*acc[i][4]; z1.y += s*acc[i][5]; z1.z += s*acc[i][6]; z1.w += s*acc[i][7];
      *(f32x4*)&C[(size_t)row*256 + col]     = z0;
      *(f32x4*)&C[(size_t)row*256 + col + 4] = z1;
    } else {
      f32x4 b0 = *(const f32x4*)&bias[col];
      f32x4 b1 = *(const f32x4*)&bias[col + 4];
      f32x4 o0 = {acc[i][0]+b0.x, acc[i][1]+b0.y, acc[i][2]+b0.z, acc[i][3]+b0.w};
      f32x4 o1 = {acc[i][4]+b1.x, acc[i][5]+b1.y, acc[i][6]+b1.z, acc[i][7]+b1.w};
      *(f32x4*)&C[(size_t)row*128 + col]     = o0;
      *(f32x4*)&C[(size_t)row*128 + col + 4] = o1;
    }
  }
}

// ---------------- fp32 flash attention v2 + fused gate ----------------------
// 512 thr (8 waves): waves 0-3 = keys [0,512), waves 4-7 = [512,1024), each
// with independent online softmax; in-block merge via LDS. Natural layouts,
// XOR slot-swizzle (slot ^= row&15) -> conflicts <= 2-way. P in registers,
// PV reads P via __shfl. Gate/Mm/PSUM update fused into the epilogue.
// LDS = 32K (Qs) + 32K (KV dbl) = exactly 64 KB.
__launch_bounds__(512, 2)
__global__ void k_attn32(const float* __restrict__ QKV, float* __restrict__ ZF,
                         float* __restrict__ Mm, float* __restrict__ PSUM,
                         const float* __restrict__ Wc, const float* __restrict__ bc){
  __shared__ float Qs[32][256];     // swizzled [q][d]; reused as merge buffer
  __shared__ float KVs[2][64][64];  // per-half K then V chunks, swizzled
  const int tid = threadIdx.x;
  const int half = tid >> 8;
  const int s = tid & 255;
  const int tx = s & 15, ty = s >> 4;
  const int lane = tid & 63;
  const int batch = blockIdx.x >> 5, qt = blockIdx.x & 31;  // consecutive blocks share batch (L2)
  const int nbase = batch*1024 + qt*32;
  const int kv0 = batch*1024;

  #pragma unroll
  for (int i = 0; i < 4; ++i){      // stage Q (coalesced, swizzled slots)
    const int q = tid >> 4;         // 0..31
    const int d4 = (tid & 15) + 16*i;
    const int ph = (d4 & 48) | ((d4 & 15) ^ (q & 15));
    *(f32x4*)&Qs[q][ph*4] = *(const f32x4*)&QKV[(size_t)(nbase + q)*768 + d4*4];
  }
  const int q0 = ty*2, q1 = q0 + 1;
  const int sw0 = q0 & 15, sw1 = q1 & 15;
  float O[2][16];
  #pragma unroll
  for (int j = 0; j < 2; ++j)
    #pragma unroll
    for (int e = 0; e < 16; ++e) O[j][e] = 0.f;
  float mr[2] = {-3.0e30f, -3.0e30f}, lr[2] = {0.f, 0.f};

  for (int t = 0; t < 8; ++t){
    const int kb = kv0 + (half*8 + t)*64;
    float S[2][4] = {{0.f,0.f,0.f,0.f},{0.f,0.f,0.f,0.f}};
    for (int dc = 0; dc < 4; ++dc){
      __syncthreads();
      #pragma unroll
      for (int i = 0; i < 4; ++i){  // stage K chunk (coalesced, swizzled)
        const int c = i*256 + s;
        const int k = c >> 4, d4c = c & 15;
        *(f32x4*)&KVs[half][k][(d4c ^ (k & 15))*4] =
            *(const f32x4*)&QKV[(size_t)(kb + k)*768 + 256 + dc*64 + d4c*4];
      }
      __syncthreads();
      #pragma unroll 4
      for (int d4c = 0; d4c < 16; ++d4c){
        const f32x4 a0 = *(const f32x4*)&Qs[q0][(dc*16 + (d4c ^ sw0))*4];
        const f32x4 a1 = *(const f32x4*)&Qs[q1][(dc*16 + (d4c ^ sw1))*4];
        #pragma unroll
        for (int e = 0; e < 4; ++e){
          const f32x4 b = *(const f32x4*)&KVs[half][e*16 + tx][(d4c ^ tx)*4];
          S[0][e] += a0.x*b.x + a0.y*b.y + a0.z*b.z + a0.w*b.w;
          S[1][e] += a1.x*b.x + a1.y*b.y + a1.z*b.z + a1.w*b.w;
        }
      }
    }
    float pp[2][4];
    #pragma unroll
    for (int j = 0; j < 2; ++j){    // online softmax per q row
      #pragma unroll
      for (int e = 0; e < 4; ++e) S[j][e] *= QK_SCALE;
      float tm = fmaxf(fmaxf(S[j][0], S[j][1]), fmaxf(S[j][2], S[j][3]));
      tm = fmaxf(tm, __shfl_xor(tm, 1));
      tm = fmaxf(tm, __shfl_xor(tm, 2));
      tm = fmaxf(tm, __shfl_xor(tm, 4));
      tm = fmaxf(tm, __shfl_xor(tm, 8));
      const float mn = fmaxf(mr[j], tm);
      const float al = expf(mr[j] - mn);
      float rs = 0.f;
      #pragma unroll
      for (int e = 0; e < 4; ++e){ pp[j][e] = expf(S[j][e] - mn); rs += pp[j][e]; }
      rs += __shfl_xor(rs, 1); rs += __shfl_xor(rs, 2);
      rs += __shfl_xor(rs, 4); rs += __shfl_xor(rs, 8);
      lr[j] = lr[j]*al + rs;
      mr[j] = mn;
      #pragma unroll
      for (int e = 0; e < 16; ++e) O[j][e] *= al;
    }
    for (int dc = 0; dc < 4; ++dc){
      __syncthreads();
      #pragma unroll
      for (int i = 0; i < 4; ++i){  // stage V chunk
        const int c = i*256 + s;
        const int k = c >> 4, d4c = c & 15;
        *(f32x4*)&KVs[half][k][(d4c ^ (k & 15))*4] =
            *(const f32x4*)&QKV[(size_t)(kb + k)*768 + 512 + dc*64 + d4c*4];
      }
      __syncthreads();
      #pragma unroll
      for (int e2 = 0; e2 < 4; ++e2){
        #pragma unroll
        for (int kk = 0; kk < 16; ++kk){
          const int src = (lane & 48) | kk;
          const float p0 = __shfl(pp[0][e2], src);
          const float p1 = __shfl(pp[1][e2], src);
          const f32x4 v = *(const f32x4*)&KVs[half][e2*16 + kk][(tx ^ kk)*4];
          O[0][dc*4+0] += p0*v.x; O[0][dc*4+1] += p0*v.y;
          O[0][dc*4+2] += p0*v.z; O[0][dc*4+3] += p0*v.w;
          O[1][dc*4+0] += p1*v.x; O[1][dc*4+1] += p1*v.y;
          O[1][dc*4+2] += p1*v.z; O[1][dc*4+3] += p1*v.w;
        }
      }
    }
  }
  // ---- merge the two key-halves ----
  __syncthreads();                  // last KVs reads done; alias as Ml
  float* Ml = (float*)KVs;          // [half*64 + q*2 + {m,l}]
  if (tx == 0){
    Ml[half*64 + q0*2 + 0] = mr[0]; Ml[half*64 + q0*2 + 1] = lr[0];
    Ml[half*64 + q1*2 + 0] = mr[1]; Ml[half*64 + q1*2 + 1] = lr[1];
  }
  __syncthreads();
  float scv[2], lcv[2];
  #pragma unroll
  for (int j = 0; j < 2; ++j){
    const int q = ty*2 + j;
    const float M0 = Ml[q*2], L0 = Ml[q*2 + 1];
    const float M1 = Ml[64 + q*2], L1 = Ml[64 + q*2 + 1];
    const float mc = fmaxf(M0, M1);
    const float s0 = expf(M0 - mc), s1 = expf(M1 - mc);
    lcv[j] = s0*L0 + s1*L1;
    scv[j] = half ? s1 : s0;
  }
  if (half == 1){                   // deposit scaled partial into dead Qs
    #pragma unroll
    for (int j = 0; j < 2; ++j)
      #pragma unroll
      for (int dc = 0; dc < 4; ++dc){
        f32x4 w = {scv[j]*O[j][dc*4+0], scv[j]*O[j][dc*4+1],
                   scv[j]*O[j][dc*4+2], scv[j]*O[j][dc*4+3]};
        *(f32x4*)&Qs[ty*2+j][dc*64 + tx*4] = w;
      }
  }
  __syncthreads();
  if (half == 0){                   // finalize + fused gate/memory/pointer
    #pragma unroll
    for (int j = 0; j < 2; ++j){
      const int q = ty*2 + j;
      const float inv = 1.f / lcv[j];
      float z[16];
      #pragma unroll
      for (int dc = 0; dc < 4; ++dc){
        const f32x4 o1 = *(const f32x4*)&Qs[q][dc*64 + tx*4];
        z[dc*4+0] = (scv[j]*O[j][dc*4+0] + o1.x)*inv;
        z[dc*4+1] = (scv[j]*O[j][dc*4+1] + o1.y)*inv;
        z[dc*4+2] = (scv[j]*O[j][dc*4+2] + o1.z)*inv;
        z[dc*4+3] = (scv[j]*O[j][dc*4+3] + o1.w)*inv;
      }
      float d0 = 0.f, d1 = 0.f, d2 = 0.f;
      #pragma unroll
      for (int dc = 0; dc < 4; ++dc)
        #pragma unroll
        for (int e = 0; e < 4; ++e){
          const int dim = dc*64 + tx*4 + e;
          const float zz = z[dc*4+e];
          d0 += zz*Wc[dim*3 + 0]; d1 += zz*Wc[dim*3 + 1]; d2 += zz*Wc[dim*3 + 2];
        }
      d0 += __shfl_xor(d0,1); d0 += __shfl_xor(d0,2); d0 += __shfl_xor(d0,4); d0 += __shfl_xor(d0,8);
      d1 += __shfl_xor(d1,1); d1 += __shfl_xor(d1,2); d1 += __shfl_xor(d1,4); d1 += __shfl_xor(d1,8);
      d2 += __shfl_xor(d2,1); d2 += __shfl_xor(d2,2); d2 += __shfl_xor(d2,4); d2 += __shfl_xor(d2,8);
      const float g0 = 1.f/(1.f + expf(-(d0 + bc[0])));
      const float g1 = 1.f/(1.f + expf(-(d1 + bc[1])));
      const float g2 = 1.f/(1.f + expf(-(d2 + bc[2])));
      const float tt = g0 + g1 + g2, tot = tt + 1e-6f;
      const float push = g0/tot, fac = tt/tot;
      if (tx == 0) PSUM[nbase + q] *= fac;
      #pragma unroll
      for (int dc = 0; dc < 4; ++dc){
        const size_t idx = (size_t)(nbase + q)*256 + dc*64 + tx*4;
        f32x4 mo = *(const f32x4*)&Mm[idx];
        mo.x += push*(z[dc*4+0] - mo.x);
        mo.y += push*(z[dc*4+1] - mo.y);
        mo.z += push*(z[dc*4+2] - mo.z);
        mo.w += push*(z[dc*4+3] - mo.w);
        *(f32x4*)&Mm[idx] = mo;
        f32x4 w = {z[dc*4+0], z[dc*4+1], z[dc*4+2], z[dc*4+3]};
        *(f32x4*)&ZF[idx] = w;
      }
    }
  }
}

// ---------------------------------------------------------------------------
extern "C" void kernel_launch(void* const* d_in, const int* in_sizes, int n_in,
                              void* d_out, int out_size, void* d_ws, size_t ws_size,
                              hipStream_t stream){
  (void)in_sizes; (void)n_in; (void)out_size; (void)ws_size;
  const float* xr   = (const float*)d_in[0];
  const float* xi   = (const float*)d_in[1];
  const float* Wq_r = (const float*)d_in[2];
  const float* Wq_i = (const float*)d_in[3];
  const float* Wk_r = (const float*)d_in[4];
  const float* Wk_i = (const float*)d_in[5];
  const float* Wv_r = (const float*)d_in[6];
  const float* Wv_i = (const float*)d_in[7];
  // d_in[8..11] (Mq_*, Mk_*) unused: all stack slots identical -> memory
  // attention exactly uniform regardless of its q/k projections (verified r3).
  const float* Mv_r = (const float*)d_in[12];
  const float* Mv_i = (const float*)d_in[13];
  const float* Wc   = (const float*)d_in[14];
  const float* bc   = (const float*)d_in[15];
  const float* Wo   = (const float*)d_in[16];
  const float* bo   = (const float*)d_in[17];

  // Workspace layout identical to verified round 3/6 (41,975,808 B).
  uint8_t* w = (uint8_t*)d_ws;
  float* Z    = (float*)w; w += (size_t)8192*256*4;   // state; aliased as ZF
  float* QKV  = (float*)w; w += (size_t)8192*768*4;
  float* Mm   = (float*)w; w += (size_t)8192*256*4;
  float* PSUM = (float*)w; w += (size_t)8192*4;
  float* ZF   = Z;  // safe alias: state dead once proj consumed it.

  k_init32<<<dim3(1024), dim3(256), 0, stream>>>(xr, xi, Z, Mm, PSUM);
  for (int t = 0; t < 8; ++t){
    k_gemm32<0><<<dim3(384), dim3(256), 0, stream>>>(Z, 6,
        Wq_r, Wq_i, Wk_r, Wk_i, Wv_r, Wv_i, QKV, nullptr, nullptr);
    k_attn32<<<dim3(256), dim3(512), 0, stream>>>(QKV, ZF, Mm, PSUM, Wc, bc);
    k_gemm32<1><<<dim3(128), dim3(256), 0, stream>>>(Mm, 2,
        Mv_r, Mv_i, nullptr, nullptr, nullptr, nullptr, Z, PSUM, nullptr);
  }
  k_gemm32<2><<<dim3(64), dim3(256), 0, stream>>>(Z, 1,
      Wo, nullptr, nullptr, nullptr, nullptr, nullptr, (float*)d_out, nullptr, bo);
}

// Round 9
// 6399.471 us; speedup vs baseline: 1.0116x; 1.0116x over previous
//
#include <hip/hip_runtime.h>
#include <stdint.h>

typedef __attribute__((ext_vector_type(4))) float f32x4;

constexpr float QK_SCALE = 0.08838834764831845f;  // 128^-0.5

// ===========================================================================
// All-fp32 pipeline (bf16 numerically forbidden: 8-step recursion amplifies
// per-step noise ~1e3-1e4; verified r3-r5). Graph identical to verified r3:
//   proj GEMM -> seq attention (+fused gate) -> memory GEMM -> out.
// Stack-memory collapse (verified r3): all K slots identical -> uniform
// memory attention -> Mq/Mk unused; read = PSUM * (Mm @ Mv_full).
// r8 lesson (measured): launch_bounds(512,2) capped VGPRs at 128 -> massive
// scratch spills (WRITE 1.09 GB/dispatch, 68x logical) for an occupancy the
// 256-block grid can never reach. Fixed to (512,1); batch mapping irrelevant
// (r7 vs r8 identical counters).
// ===========================================================================

__global__ void k_init32(const float* __restrict__ xr, const float* __restrict__ xi,
                         float* __restrict__ Z, float* __restrict__ Mm,
                         float* __restrict__ PSUM){
  for (int i = blockIdx.x*blockDim.x + threadIdx.x; i < 8192*256; i += gridDim.x*blockDim.x){
    int n = i >> 8, d = i & 255;
    Z[i]  = (d < 128) ? xr[n*128 + d] : xi[n*128 + d - 128];
    Mm[i] = 0.f;
    if (i < 8192) PSUM[i] = 1.f;
  }
}

// ---------------- tiled fp32 GEMM (unchanged from verified r6) --------------
template<int EPI>
__launch_bounds__(256, 2)
__global__ void k_gemm32(const float* __restrict__ A, int nb,
                         const float* __restrict__ W0r, const float* __restrict__ W0i,
                         const float* __restrict__ W1r, const float* __restrict__ W1i,
                         const float* __restrict__ W2r, const float* __restrict__ W2i,
                         float* __restrict__ C, const float* __restrict__ PSUM,
                         const float* __restrict__ bias){
  __shared__ float As[32][132];   // [k][m], padded
  __shared__ float Bs[32][132];   // [k][n], padded
  const int bx = blockIdx.x % nb, by = blockIdx.x / nb;
  const int m0 = by << 7, n0 = bx << 7;
  const int tid = threadIdx.x;
  const int tx = tid & 15, ty = tid >> 4;
  const float* Wr = W0r; const float* Wi = W0i;
  if constexpr (EPI == 0){
    int sec = n0 >> 8;
    Wr = (sec == 0) ? W0r : (sec == 1) ? W1r : W2r;
    Wi = (sec == 0) ? W0i : (sec == 1) ? W1i : W2i;
  }
  const int hn = (n0 >> 7) & 1;
  float acc[8][8];
  #pragma unroll
  for (int i = 0; i < 8; ++i)
    #pragma unroll
    for (int j = 0; j < 8; ++j) acc[i][j] = 0.f;

  for (int kt = 0; kt < 8; ++kt){
    if (kt) __syncthreads();
    #pragma unroll
    for (int i = 0; i < 4; ++i){               // A tile: transpose-scatter
      int c = i*256 + tid;
      int row = c >> 3, k4 = c & 7;
      f32x4 v = *(const f32x4*)&A[(size_t)(m0 + row)*256 + kt*32 + k4*4];
      As[k4*4+0][row] = v.x; As[k4*4+1][row] = v.y;
      As[k4*4+2][row] = v.z; As[k4*4+3][row] = v.w;
    }
    #pragma unroll
    for (int i = 0; i < 4; ++i){               // B tile: on-the-fly Wfull
      int c = i*256 + tid;
      int k = c >> 5, n4 = c & 31;
      int gk = kt*32 + k;
      f32x4 v;
      if constexpr (EPI == 2){
        v = *(const f32x4*)&W0r[(size_t)gk*128 + n4*4];
      } else {
        int hk = gk >> 7, kk = gk & 127;
        const float* src = ((hk ^ hn) == 0) ? Wr : Wi;
        v = *(const f32x4*)&src[(size_t)kk*128 + n4*4];
        if (hk == 1 && hn == 0){ v.x = -v.x; v.y = -v.y; v.z = -v.z; v.w = -v.w; }
      }
      *(f32x4*)&Bs[k][n4*4] = v;
    }
    __syncthreads();
    #pragma unroll 8
    for (int k = 0; k < 32; ++k){
      float a[8], b[8];
      *(f32x4*)&a[0] = *(const f32x4*)&As[k][ty*8];
      *(f32x4*)&a[4] = *(const f32x4*)&As[k][ty*8 + 4];
      *(f32x4*)&b[0] = *(const f32x4*)&Bs[k][tx*8];
      *(f32x4*)&b[4] = *(const f32x4*)&Bs[k][tx*8 + 4];
      #pragma unroll
      for (int i = 0; i < 8; ++i)
        #pragma unroll
        for (int j = 0; j < 8; ++j) acc[i][j] += a[i]*b[j];
    }
  }
  #pragma unroll
  for (int i = 0; i < 8; ++i){
    const int row = m0 + ty*8 + i;
    const int col = n0 + tx*8;
    if constexpr (EPI == 0){
      *(f32x4*)&C[(size_t)row*768 + col]     = *(const f32x4*)&acc[i][0];
      *(f32x4*)&C[(size_t)row*768 + col + 4] = *(const f32x4*)&acc[i][4];
    } else if constexpr (EPI == 1){
      const float s = 0.1f * PSUM[row];
      f32x4 z0 = *(const f32x4*)&C[(size_t)row*256 + col];
      f32x4 z1 = *(const f32x4*)&C[(size_t)row*256 + col + 4];
      z0.x += s*acc[i][0]; z0.y += s*acc[i][1]; z0.z += s*acc[i][2]; z0.w += s*acc[i][3];
      z1.x += s*acc[i][4]; z1.y += s*acc[i][5]; z1.z += s*acc[i][6]; z1.w += s*acc[i][7];
      *(f32x4*)&C[(size_t)row*256 + col]     = z0;
      *(f32x4*)&C[(size_t)row*256 + col + 4] = z1;
    } else {
      f32x4 b0 = *(const f32x4*)&bias[col];
      f32x4 b1 = *(const f32x4*)&bias[col + 4];
      f32x4 o0 = {acc[i][0]+b0.x, acc[i][1]+b0.y, acc[i][2]+b0.z, acc[i][3]+b0.w};
      f32x4 o1 = {acc[i][4]+b1.x, acc[i][5]+b1.y, acc[i][6]+b1.z, acc[i][7]+b1.w};
      *(f32x4*)&C[(size_t)row*128 + col]     = o0;
      *(f32x4*)&C[(size_t)row*128 + col + 4] = o1;
    }
  }
}

// ---------------- fp32 flash attention v2 + fused gate ----------------------
// 512 thr (8 waves): waves 0-3 = keys [0,512), waves 4-7 = [512,1024), each
// with independent online softmax; in-block merge via LDS. Natural layouts,
// XOR slot-swizzle (slot ^= row&15) -> conflicts <= 2-way. P in registers,
// PV reads P via __shfl. Gate/Mm/PSUM update fused into the epilogue.
// LDS = 32K (Qs) + 32K (KV) = 64 KB. launch_bounds (512,1): grid is 1
// block/CU, so allow the full 256-VGPR budget (r8: (512,2) caused spills).
__launch_bounds__(512, 1)
__global__ void k_attn32(const float* __restrict__ QKV, float* __restrict__ ZF,
                         float* __restrict__ Mm, float* __restrict__ PSUM,
                         const float* __restrict__ Wc, const float* __restrict__ bc){
  __shared__ float Qs[32][256];     // swizzled [q][d]; reused as merge buffer
  __shared__ float KVs[2][64][64];  // per-half K then V chunks, swizzled
  const int tid = threadIdx.x;
  const int half = tid >> 8;
  const int s = tid & 255;
  const int tx = s & 15, ty = s >> 4;
  const int lane = tid & 63;
  const int batch = blockIdx.x >> 5, qt = blockIdx.x & 31;  // consecutive blocks share batch
  const int nbase = batch*1024 + qt*32;
  const int kv0 = batch*1024;

  #pragma unroll
  for (int i = 0; i < 4; ++i){      // stage Q (coalesced, swizzled slots)
    const int q = tid >> 4;         // 0..31
    const int d4 = (tid & 15) + 16*i;
    const int ph = (d4 & 48) | ((d4 & 15) ^ (q & 15));
    *(f32x4*)&Qs[q][ph*4] = *(const f32x4*)&QKV[(size_t)(nbase + q)*768 + d4*4];
  }
  const int q0 = ty*2, q1 = q0 + 1;
  const int sw0 = q0 & 15, sw1 = q1 & 15;
  float O[2][16];
  #pragma unroll
  for (int j = 0; j < 2; ++j)
    #pragma unroll
    for (int e = 0; e < 16; ++e) O[j][e] = 0.f;
  float mr[2] = {-3.0e30f, -3.0e30f}, lr[2] = {0.f, 0.f};

  for (int t = 0; t < 8; ++t){
    const int kb = kv0 + (half*8 + t)*64;
    float S[2][4] = {{0.f,0.f,0.f,0.f},{0.f,0.f,0.f,0.f}};
    for (int dc = 0; dc < 4; ++dc){
      __syncthreads();
      #pragma unroll
      for (int i = 0; i < 4; ++i){  // stage K chunk (coalesced, swizzled)
        const int c = i*256 + s;
        const int k = c >> 4, d4c = c & 15;
        *(f32x4*)&KVs[half][k][(d4c ^ (k & 15))*4] =
            *(const f32x4*)&QKV[(size_t)(kb + k)*768 + 256 + dc*64 + d4c*4];
      }
      __syncthreads();
      #pragma unroll 4
      for (int d4c = 0; d4c < 16; ++d4c){
        const f32x4 a0 = *(const f32x4*)&Qs[q0][(dc*16 + (d4c ^ sw0))*4];
        const f32x4 a1 = *(const f32x4*)&Qs[q1][(dc*16 + (d4c ^ sw1))*4];
        #pragma unroll
        for (int e = 0; e < 4; ++e){
          const f32x4 b = *(const f32x4*)&KVs[half][e*16 + tx][(d4c ^ tx)*4];
          S[0][e] += a0.x*b.x + a0.y*b.y + a0.z*b.z + a0.w*b.w;
          S[1][e] += a1.x*b.x + a1.y*b.y + a1.z*b.z + a1.w*b.w;
        }
      }
    }
    float pp[2][4];
    #pragma unroll
    for (int j = 0; j < 2; ++j){    // online softmax per q row
      #pragma unroll
      for (int e = 0; e < 4; ++e) S[j][e] *= QK_SCALE;
      float tm = fmaxf(fmaxf(S[j][0], S[j][1]), fmaxf(S[j][2], S[j][3]));
      tm = fmaxf(tm, __shfl_xor(tm, 1));
      tm = fmaxf(tm, __shfl_xor(tm, 2));
      tm = fmaxf(tm, __shfl_xor(tm, 4));
      tm = fmaxf(tm, __shfl_xor(tm, 8));
      const float mn = fmaxf(mr[j], tm);
      const float al = expf(mr[j] - mn);
      float rs = 0.f;
      #pragma unroll
      for (int e = 0; e < 4; ++e){ pp[j][e] = expf(S[j][e] - mn); rs += pp[j][e]; }
      rs += __shfl_xor(rs, 1); rs += __shfl_xor(rs, 2);
      rs += __shfl_xor(rs, 4); rs += __shfl_xor(rs, 8);
      lr[j] = lr[j]*al + rs;
      mr[j] = mn;
      #pragma unroll
      for (int e = 0; e < 16; ++e) O[j][e] *= al;
    }
    for (int dc = 0; dc < 4; ++dc){
      __syncthreads();
      #pragma unroll
      for (int i = 0; i < 4; ++i){  // stage V chunk
        const int c = i*256 + s;
        const int k = c >> 4, d4c = c & 15;
        *(f32x4*)&KVs[half][k][(d4c ^ (k & 15))*4] =
            *(const f32x4*)&QKV[(size_t)(kb + k)*768 + 512 + dc*64 + d4c*4];
      }
      __syncthreads();
      #pragma unroll
      for (int e2 = 0; e2 < 4; ++e2){
        #pragma unroll
        for (int kk = 0; kk < 16; ++kk){
          const int src = (lane & 48) | kk;
          const float p0 = __shfl(pp[0][e2], src);
          const float p1 = __shfl(pp[1][e2], src);
          const f32x4 v = *(const f32x4*)&KVs[half][e2*16 + kk][(tx ^ kk)*4];
          O[0][dc*4+0] += p0*v.x; O[0][dc*4+1] += p0*v.y;
          O[0][dc*4+2] += p0*v.z; O[0][dc*4+3] += p0*v.w;
          O[1][dc*4+0] += p1*v.x; O[1][dc*4+1] += p1*v.y;
          O[1][dc*4+2] += p1*v.z; O[1][dc*4+3] += p1*v.w;
        }
      }
    }
  }
  // ---- merge the two key-halves ----
  __syncthreads();                  // last KVs reads done; alias as Ml
  float* Ml = (float*)KVs;          // [half*64 + q*2 + {m,l}]
  if (tx == 0){
    Ml[half*64 + q0*2 + 0] = mr[0]; Ml[half*64 + q0*2 + 1] = lr[0];
    Ml[half*64 + q1*2 + 0] = mr[1]; Ml[half*64 + q1*2 + 1] = lr[1];
  }
  __syncthreads();
  float scv[2], lcv[2];
  #pragma unroll
  for (int j = 0; j < 2; ++j){
    const int q = ty*2 + j;
    const float M0 = Ml[q*2], L0 = Ml[q*2 + 1];
    const float M1 = Ml[64 + q*2], L1 = Ml[64 + q*2 + 1];
    const float mc = fmaxf(M0, M1);
    const float s0 = expf(M0 - mc), s1 = expf(M1 - mc);
    lcv[j] = s0*L0 + s1*L1;
    scv[j] = half ? s1 : s0;
  }
  if (half == 1){                   // deposit scaled partial into dead Qs
    #pragma unroll
    for (int j = 0; j < 2; ++j)
      #pragma unroll
      for (int dc = 0; dc < 4; ++dc){
        f32x4 w = {scv[j]*O[j][dc*4+0], scv[j]*O[j][dc*4+1],
                   scv[j]*O[j][dc*4+2], scv[j]*O[j][dc*4+3]};
        *(f32x4*)&Qs[ty*2+j][dc*64 + tx*4] = w;
      }
  }
  __syncthreads();
  if (half == 0){                   // finalize + fused gate/memory/pointer
    #pragma unroll
    for (int j = 0; j < 2; ++j){
      const int q = ty*2 + j;
      const float inv = 1.f / lcv[j];
      float z[16];
      #pragma unroll
      for (int dc = 0; dc < 4; ++dc){
        const f32x4 o1 = *(const f32x4*)&Qs[q][dc*64 + tx*4];
        z[dc*4+0] = (scv[j]*O[j][dc*4+0] + o1.x)*inv;
        z[dc*4+1] = (scv[j]*O[j][dc*4+1] + o1.y)*inv;
        z[dc*4+2] = (scv[j]*O[j][dc*4+2] + o1.z)*inv;
        z[dc*4+3] = (scv[j]*O[j][dc*4+3] + o1.w)*inv;
      }
      float d0 = 0.f, d1 = 0.f, d2 = 0.f;
      #pragma unroll
      for (int dc = 0; dc < 4; ++dc)
        #pragma unroll
        for (int e = 0; e < 4; ++e){
          const int dim = dc*64 + tx*4 + e;
          const float zz = z[dc*4+e];
          d0 += zz*Wc[dim*3 + 0]; d1 += zz*Wc[dim*3 + 1]; d2 += zz*Wc[dim*3 + 2];
        }
      d0 += __shfl_xor(d0,1); d0 += __shfl_xor(d0,2); d0 += __shfl_xor(d0,4); d0 += __shfl_xor(d0,8);
      d1 += __shfl_xor(d1,1); d1 += __shfl_xor(d1,2); d1 += __shfl_xor(d1,4); d1 += __shfl_xor(d1,8);
      d2 += __shfl_xor(d2,1); d2 += __shfl_xor(d2,2); d2 += __shfl_xor(d2,4); d2 += __shfl_xor(d2,8);
      const float g0 = 1.f/(1.f + expf(-(d0 + bc[0])));
      const float g1 = 1.f/(1.f + expf(-(d1 + bc[1])));
      const float g2 = 1.f/(1.f + expf(-(d2 + bc[2])));
      const float tt = g0 + g1 + g2, tot = tt + 1e-6f;
      const float push = g0/tot, fac = tt/tot;
      if (tx == 0) PSUM[nbase + q] *= fac;
      #pragma unroll
      for (int dc = 0; dc < 4; ++dc){
        const size_t idx = (size_t)(nbase + q)*256 + dc*64 + tx*4;
        f32x4 mo = *(const f32x4*)&Mm[idx];
        mo.x += push*(z[dc*4+0] - mo.x);
        mo.y += push*(z[dc*4+1] - mo.y);
        mo.z += push*(z[dc*4+2] - mo.z);
        mo.w += push*(z[dc*4+3] - mo.w);
        *(f32x4*)&Mm[idx] = mo;
        f32x4 w = {z[dc*4+0], z[dc*4+1], z[dc*4+2], z[dc*4+3]};
        *(f32x4*)&ZF[idx] = w;
      }
    }
  }
}

// ---------------------------------------------------------------------------
extern "C" void kernel_launch(void* const* d_in, const int* in_sizes, int n_in,
                              void* d_out, int out_size, void* d_ws, size_t ws_size,
                              hipStream_t stream){
  (void)in_sizes; (void)n_in; (void)out_size; (void)ws_size;
  const float* xr   = (const float*)d_in[0];
  const float* xi   = (const float*)d_in[1];
  const float* Wq_r = (const float*)d_in[2];
  const float* Wq_i = (const float*)d_in[3];
  const float* Wk_r = (const float*)d_in[4];
  const float* Wk_i = (const float*)d_in[5];
  const float* Wv_r = (const float*)d_in[6];
  const float* Wv_i = (const float*)d_in[7];
  // d_in[8..11] (Mq_*, Mk_*) unused: all stack slots identical -> memory
  // attention exactly uniform regardless of its q/k projections (verified r3).
  const float* Mv_r = (const float*)d_in[12];
  const float* Mv_i = (const float*)d_in[13];
  const float* Wc   = (const float*)d_in[14];
  const float* bc   = (const float*)d_in[15];
  const float* Wo   = (const float*)d_in[16];
  const float* bo   = (const float*)d_in[17];

  // Workspace layout identical to verified round 3/6 (41,975,808 B).
  uint8_t* w = (uint8_t*)d_ws;
  float* Z    = (float*)w; w += (size_t)8192*256*4;   // state; aliased as ZF
  float* QKV  = (float*)w; w += (size_t)8192*768*4;
  float* Mm   = (float*)w; w += (size_t)8192*256*4;
  float* PSUM = (float*)w; w += (size_t)8192*4;
  float* ZF   = Z;  // safe alias: state dead once proj consumed it.

  k_init32<<<dim3(1024), dim3(256), 0, stream>>>(xr, xi, Z, Mm, PSUM);
  for (int t = 0; t < 8; ++t){
    k_gemm32<0><<<dim3(384), dim3(256), 0, stream>>>(Z, 6,
        Wq_r, Wq_i, Wk_r, Wk_i, Wv_r, Wv_i, QKV, nullptr, nullptr);
    k_attn32<<<dim3(256), dim3(512), 0, stream>>>(QKV, ZF, Mm, PSUM, Wc, bc);
    k_gemm32<1><<<dim3(128), dim3(256), 0, stream>>>(Mm, 2,
        Mv_r, Mv_i, nullptr, nullptr, nullptr, nullptr, Z, PSUM, nullptr);
  }
  k_gemm32<2><<<dim3(64), dim3(256), 0, stream>>>(Z, 1,
      Wo, nullptr, nullptr, nullptr, nullptr, nullptr, (float*)d_out, nullptr, bo);
}

// Round 10
// 5813.339 us; speedup vs baseline: 1.1136x; 1.1008x over previous
//
#include <hip/hip_runtime.h>
#include <stdint.h>

typedef __attribute__((ext_vector_type(4))) float f32x4;

constexpr float QK_SCALE = 0.08838834764831845f;  // 128^-0.5

// ===========================================================================
// All-fp32 pipeline (bf16 numerically forbidden: 8-step recursion amplifies
// per-step noise ~1e3-1e4; verified r3-r5). Graph identical to verified r3:
//   proj GEMM -> seq attention -> gate -> memory GEMM -> out.
// Stack-memory collapse (verified r3): all K slots identical -> uniform
// memory attention -> Mq/Mk unused; read = PSUM * (Mm @ Mv_full).
// r7-r9 lesson (measured): the 512-thr fused monolith spills (~8KB/thread
// scratch, WRITE 1.09GB) at a pinned 128 VGPR regardless of launch_bounds.
// This round returns to the r6 256-thr shape (92 VGPR, WRITE 8MB clean) and
// fixes ONLY its measured defects: transpose-staging bank conflicts (3.4e7)
// -> swizzled natural layout; grid 256 (1 blk/CU, 11.5% occ) -> 16-row
// q-tiles, grid 512, 32KB LDS (2 blk/CU).
// ===========================================================================

__global__ void k_init32(const float* __restrict__ xr, const float* __restrict__ xi,
                         float* __restrict__ Z, float* __restrict__ Mm,
                         float* __restrict__ PSUM){
  for (int i = blockIdx.x*blockDim.x + threadIdx.x; i < 8192*256; i += gridDim.x*blockDim.x){
    int n = i >> 8, d = i & 255;
    Z[i]  = (d < 128) ? xr[n*128 + d] : xi[n*128 + d - 128];
    Mm[i] = 0.f;
    if (i < 8192) PSUM[i] = 1.f;
  }
}

// ---------------- tiled fp32 GEMM (unchanged from verified r6) --------------
template<int EPI>
__launch_bounds__(256, 2)
__global__ void k_gemm32(const float* __restrict__ A, int nb,
                         const float* __restrict__ W0r, const float* __restrict__ W0i,
                         const float* __restrict__ W1r, const float* __restrict__ W1i,
                         const float* __restrict__ W2r, const float* __restrict__ W2i,
                         float* __restrict__ C, const float* __restrict__ PSUM,
                         const float* __restrict__ bias){
  __shared__ float As[32][132];   // [k][m], padded
  __shared__ float Bs[32][132];   // [k][n], padded
  const int bx = blockIdx.x % nb, by = blockIdx.x / nb;
  const int m0 = by << 7, n0 = bx << 7;
  const int tid = threadIdx.x;
  const int tx = tid & 15, ty = tid >> 4;
  const float* Wr = W0r; const float* Wi = W0i;
  if constexpr (EPI == 0){
    int sec = n0 >> 8;
    Wr = (sec == 0) ? W0r : (sec == 1) ? W1r : W2r;
    Wi = (sec == 0) ? W0i : (sec == 1) ? W1i : W2i;
  }
  const int hn = (n0 >> 7) & 1;
  float acc[8][8];
  #pragma unroll
  for (int i = 0; i < 8; ++i)
    #pragma unroll
    for (int j = 0; j < 8; ++j) acc[i][j] = 0.f;

  for (int kt = 0; kt < 8; ++kt){
    if (kt) __syncthreads();
    #pragma unroll
    for (int i = 0; i < 4; ++i){               // A tile: transpose-scatter
      int c = i*256 + tid;
      int row = c >> 3, k4 = c & 7;
      f32x4 v = *(const f32x4*)&A[(size_t)(m0 + row)*256 + kt*32 + k4*4];
      As[k4*4+0][row] = v.x; As[k4*4+1][row] = v.y;
      As[k4*4+2][row] = v.z; As[k4*4+3][row] = v.w;
    }
    #pragma unroll
    for (int i = 0; i < 4; ++i){               // B tile: on-the-fly Wfull
      int c = i*256 + tid;
      int k = c >> 5, n4 = c & 31;
      int gk = kt*32 + k;
      f32x4 v;
      if constexpr (EPI == 2){
        v = *(const f32x4*)&W0r[(size_t)gk*128 + n4*4];
      } else {
        int hk = gk >> 7, kk = gk & 127;
        const float* src = ((hk ^ hn) == 0) ? Wr : Wi;
        v = *(const f32x4*)&src[(size_t)kk*128 + n4*4];
        if (hk == 1 && hn == 0){ v.x = -v.x; v.y = -v.y; v.z = -v.z; v.w = -v.w; }
      }
      *(f32x4*)&Bs[k][n4*4] = v;
    }
    __syncthreads();
    #pragma unroll 8
    for (int k = 0; k < 32; ++k){
      float a[8], b[8];
      *(f32x4*)&a[0] = *(const f32x4*)&As[k][ty*8];
      *(f32x4*)&a[4] = *(const f32x4*)&As[k][ty*8 + 4];
      *(f32x4*)&b[0] = *(const f32x4*)&Bs[k][tx*8];
      *(f32x4*)&b[4] = *(const f32x4*)&Bs[k][tx*8 + 4];
      #pragma unroll
      for (int i = 0; i < 8; ++i)
        #pragma unroll
        for (int j = 0; j < 8; ++j) acc[i][j] += a[i]*b[j];
    }
  }
  #pragma unroll
  for (int i = 0; i < 8; ++i){
    const int row = m0 + ty*8 + i;
    const int col = n0 + tx*8;
    if constexpr (EPI == 0){
      *(f32x4*)&C[(size_t)row*768 + col]     = *(const f32x4*)&acc[i][0];
      *(f32x4*)&C[(size_t)row*768 + col + 4] = *(const f32x4*)&acc[i][4];
    } else if constexpr (EPI == 1){
      const float s = 0.1f * PSUM[row];
      f32x4 z0 = *(const f32x4*)&C[(size_t)row*256 + col];
      f32x4 z1 = *(const f32x4*)&C[(size_t)row*256 + col + 4];
      z0.x += s*acc[i][0]; z0.y += s*acc[i][1]; z0.z += s*acc[i][2]; z0.w += s*acc[i][3];
      z1.x += s*acc[i][4]; z1.y += s*acc[i][5]; z1.z += s*acc[i][6]; z1.w += s*acc[i][7];
      *(f32x4*)&C[(size_t)row*256 + col]     = z0;
      *(f32x4*)&C[(size_t)row*256 + col + 4] = z1;
    } else {
      f32x4 b0 = *(const f32x4*)&bias[col];
      f32x4 b1 = *(const f32x4*)&bias[col + 4];
      f32x4 o0 = {acc[i][0]+b0.x, acc[i][1]+b0.y, acc[i][2]+b0.z, acc[i][3]+b0.w};
      f32x4 o1 = {acc[i][4]+b1.x, acc[i][5]+b1.y, acc[i][6]+b1.z, acc[i][7]+b1.w};
      *(f32x4*)&C[(size_t)row*128 + col]     = o0;
      *(f32x4*)&C[(size_t)row*128 + col + 4] = o1;
    }
  }
}

// ---------------- fp32 flash attention v3 -----------------------------------
// 256 thr (4 waves), 16 q-rows per block (1 row/thread: q = ty), grid 512.
// Keys serial in 16 tiles of 64, staged in 64x64 dc-chunks. Natural layouts
// with XOR slot-swizzle (slot ^= row&15): staging and reads conflict-free /
// 2-way max. P in registers; PV fetches P via __shfl from the tx==kk lane.
// LDS = 16KB (Qs) + 16KB (KVs) = 32KB -> 2 blocks/CU at grid 512.
__launch_bounds__(256, 2)
__global__ void k_attn32(const float* __restrict__ QKV, float* __restrict__ ZF){
  __shared__ float Qs[16][256];    // swizzled [q][d]
  __shared__ float KVs[64][64];    // swizzled chunk [row][d]
  const int tid = threadIdx.x;
  const int tx = tid & 15, ty = tid >> 4;   // ty = q row (0..15)
  const int lane = tid & 63;
  const int batch = blockIdx.x >> 6, qt = blockIdx.x & 63;  // consecutive blocks share batch
  const int nbase = batch*1024 + qt*16;
  const int kv0 = batch*1024;

  #pragma unroll
  for (int i = 0; i < 4; ++i){      // stage Q (coalesced, swizzled slots)
    const int q = tid >> 4;
    const int d4 = (tid & 15) + 16*i;
    const int ph = (d4 & 48) | ((d4 & 15) ^ (q & 15));
    *(f32x4*)&Qs[q][ph*4] = *(const f32x4*)&QKV[(size_t)(nbase + q)*768 + d4*4];
  }
  const int q = ty, sw = ty & 15;
  float O[16];
  #pragma unroll
  for (int e = 0; e < 16; ++e) O[e] = 0.f;
  float mr = -3.0e30f, lr = 0.f;

  for (int t = 0; t < 16; ++t){
    const int kb = kv0 + t*64;
    float S[4] = {0.f, 0.f, 0.f, 0.f};
    for (int dc = 0; dc < 4; ++dc){
      __syncthreads();                        // prev chunk reads done (covers Q stage at t=0)
      #pragma unroll
      for (int i = 0; i < 4; ++i){            // stage K chunk (swizzled)
        const int c = i*256 + tid;
        const int k = c >> 4, d4c = c & 15;
        *(f32x4*)&KVs[k][(d4c ^ (k & 15))*4] =
            *(const f32x4*)&QKV[(size_t)(kb + k)*768 + 256 + dc*64 + d4c*4];
      }
      __syncthreads();
      #pragma unroll 4
      for (int d4c = 0; d4c < 16; ++d4c){
        const f32x4 a = *(const f32x4*)&Qs[q][(dc*16 + (d4c ^ sw))*4];
        #pragma unroll
        for (int e = 0; e < 4; ++e){
          const f32x4 b = *(const f32x4*)&KVs[e*16 + tx][(d4c ^ tx)*4];
          S[e] += a.x*b.x + a.y*b.y + a.z*b.z + a.w*b.w;
        }
      }
    }
    // ---- online softmax (row q; its 16 lanes are the tx group) ----
    float pp[4];
    #pragma unroll
    for (int e = 0; e < 4; ++e) S[e] *= QK_SCALE;
    float tm = fmaxf(fmaxf(S[0], S[1]), fmaxf(S[2], S[3]));
    tm = fmaxf(tm, __shfl_xor(tm, 1));
    tm = fmaxf(tm, __shfl_xor(tm, 2));
    tm = fmaxf(tm, __shfl_xor(tm, 4));
    tm = fmaxf(tm, __shfl_xor(tm, 8));
    const float mn = fmaxf(mr, tm);
    const float al = expf(mr - mn);
    float rs = 0.f;
    #pragma unroll
    for (int e = 0; e < 4; ++e){ pp[e] = expf(S[e] - mn); rs += pp[e]; }
    rs += __shfl_xor(rs, 1); rs += __shfl_xor(rs, 2);
    rs += __shfl_xor(rs, 4); rs += __shfl_xor(rs, 8);
    lr = lr*al + rs;
    mr = mn;
    #pragma unroll
    for (int e = 0; e < 16; ++e) O[e] *= al;
    // ---- PV ----
    for (int dc = 0; dc < 4; ++dc){
      __syncthreads();
      #pragma unroll
      for (int i = 0; i < 4; ++i){            // stage V chunk (swizzled)
        const int c = i*256 + tid;
        const int k = c >> 4, d4c = c & 15;
        *(f32x4*)&KVs[k][(d4c ^ (k & 15))*4] =
            *(const f32x4*)&QKV[(size_t)(kb + k)*768 + 512 + dc*64 + d4c*4];
      }
      __syncthreads();
      #pragma unroll
      for (int e2 = 0; e2 < 4; ++e2){
        #pragma unroll
        for (int kk = 0; kk < 16; ++kk){
          const int src = (lane & 48) | kk;   // lane with tx==kk, same q
          const float p = __shfl(pp[e2], src);
          const f32x4 v = *(const f32x4*)&KVs[e2*16 + kk][(tx ^ kk)*4];
          O[dc*4+0] += p*v.x; O[dc*4+1] += p*v.y;
          O[dc*4+2] += p*v.z; O[dc*4+3] += p*v.w;
        }
      }
    }
  }
  const float inv = 1.f / lr;
  #pragma unroll
  for (int dc = 0; dc < 4; ++dc){
    f32x4 w = {O[dc*4+0]*inv, O[dc*4+1]*inv, O[dc*4+2]*inv, O[dc*4+3]*inv};
    *(f32x4*)&ZF[(size_t)(nbase + q)*256 + dc*64 + tx*4] = w;
  }
}

// ---------------- gate + memory + pointer-mass (verified round-3) -----------
__global__ void n_gate(const float* __restrict__ ZF,
                       const float* __restrict__ Wc, const float* __restrict__ bc,
                       float* __restrict__ Mm, float* __restrict__ PSUM){
  __shared__ float r0[256], r1[256], r2[256];
  __shared__ float push_s;
  const int n = blockIdx.x, t = threadIdx.x;
  const float z = ZF[n*256 + t];
  r0[t] = z*Wc[t*3 + 0];
  r1[t] = z*Wc[t*3 + 1];
  r2[t] = z*Wc[t*3 + 2];
  __syncthreads();
  for (int s2 = 128; s2 > 0; s2 >>= 1){
    if (t < s2){ r0[t] += r0[t+s2]; r1[t] += r1[t+s2]; r2[t] += r2[t+s2]; }
    __syncthreads();
  }
  if (t == 0){
    float g0 = 1.f/(1.f + expf(-(r0[0] + bc[0])));
    float g1 = 1.f/(1.f + expf(-(r1[0] + bc[1])));
    float g2 = 1.f/(1.f + expf(-(r2[0] + bc[2])));
    float tt = g0 + g1 + g2, tot = tt + 1e-6f;
    push_s = g0/tot;
    PSUM[n] *= tt/tot;           // pointer mass with the NEW gates
  }
  __syncthreads();
  const float mo = Mm[n*256 + t];
  Mm[n*256 + t] = mo + push_s*(z - mo);   // (1-push)*m + push*zf
}

// ---------------------------------------------------------------------------
extern "C" void kernel_launch(void* const* d_in, const int* in_sizes, int n_in,
                              void* d_out, int out_size, void* d_ws, size_t ws_size,
                              hipStream_t stream){
  (void)in_sizes; (void)n_in; (void)out_size; (void)ws_size;
  const float* xr   = (const float*)d_in[0];
  const float* xi   = (const float*)d_in[1];
  const float* Wq_r = (const float*)d_in[2];
  const float* Wq_i = (const float*)d_in[3];
  const float* Wk_r = (const float*)d_in[4];
  const float* Wk_i = (const float*)d_in[5];
  const float* Wv_r = (const float*)d_in[6];
  const float* Wv_i = (const float*)d_in[7];
  // d_in[8..11] (Mq_*, Mk_*) unused: all stack slots identical -> memory
  // attention exactly uniform regardless of its q/k projections (verified r3).
  const float* Mv_r = (const float*)d_in[12];
  const float* Mv_i = (const float*)d_in[13];
  const float* Wc   = (const float*)d_in[14];
  const float* bc   = (const float*)d_in[15];
  const float* Wo   = (const float*)d_in[16];
  const float* bo   = (const float*)d_in[17];

  // Workspace layout identical to verified round 3/6 (41,975,808 B).
  uint8_t* w = (uint8_t*)d_ws;
  float* Z    = (float*)w; w += (size_t)8192*256*4;   // state; aliased as ZF
  float* QKV  = (float*)w; w += (size_t)8192*768*4;
  float* Mm   = (float*)w; w += (size_t)8192*256*4;
  float* PSUM = (float*)w; w += (size_t)8192*4;
  float* ZF   = Z;  // safe alias: state dead once proj consumed it.

  k_init32<<<dim3(1024), dim3(256), 0, stream>>>(xr, xi, Z, Mm, PSUM);
  for (int t = 0; t < 8; ++t){
    k_gemm32<0><<<dim3(384), dim3(256), 0, stream>>>(Z, 6,
        Wq_r, Wq_i, Wk_r, Wk_i, Wv_r, Wv_i, QKV, nullptr, nullptr);
    k_attn32<<<dim3(512), dim3(256), 0, stream>>>(QKV, ZF);
    n_gate<<<dim3(8192), dim3(256), 0, stream>>>(ZF, Wc, bc, Mm, PSUM);
    k_gemm32<1><<<dim3(128), dim3(256), 0, stream>>>(Mm, 2,
        Mv_r, Mv_i, nullptr, nullptr, nullptr, nullptr, Z, PSUM, nullptr);
  }
  k_gemm32<2><<<dim3(64), dim3(256), 0, stream>>>(Z, 1,
      Wo, nullptr, nullptr, nullptr, nullptr, nullptr, (float*)d_out, nullptr, bo);
}

// Round 11
// 3201.696 us; speedup vs baseline: 2.0219x; 1.8157x over previous
//
#include <hip/hip_runtime.h>
#include <stdint.h>

typedef __attribute__((ext_vector_type(4))) float f32x4;

constexpr float QK_SCALE = 0.08838834764831845f;  // 128^-0.5

// ===========================================================================
// All-fp32 pipeline (bf16 numerically forbidden: 8-step recursion amplifies
// per-step noise ~1e3-1e4; verified r3-r5). Graph identical to verified r3.
// Stack-memory collapse (verified r3): all K slots identical -> uniform
// memory attention -> Mq/Mk unused; read = PSUM * (Mm @ Mv_full).
// r10 lesson (measured): flash attn was LDS-issue-bound at ~3 FMA per LDS
// instr (VALUBusy 43%, 656us). This round: GEMM-style register tiles
// (4 rows x 4 keys QK, 4 rows x 8 dims PV) -> ~8-10 FMA/LDS instr.
// ===========================================================================

__global__ void k_init32(const float* __restrict__ xr, const float* __restrict__ xi,
                         float* __restrict__ Z, float* __restrict__ Mm,
                         float* __restrict__ PSUM){
  for (int i = blockIdx.x*blockDim.x + threadIdx.x; i < 8192*256; i += gridDim.x*blockDim.x){
    int n = i >> 8, d = i & 255;
    Z[i]  = (d < 128) ? xr[n*128 + d] : xi[n*128 + d - 128];
    Mm[i] = 0.f;
    if (i < 8192) PSUM[i] = 1.f;
  }
}

// ---------------- tiled fp32 GEMM (unchanged from verified r6) --------------
template<int EPI>
__launch_bounds__(256, 2)
__global__ void k_gemm32(const float* __restrict__ A, int nb,
                         const float* __restrict__ W0r, const float* __restrict__ W0i,
                         const float* __restrict__ W1r, const float* __restrict__ W1i,
                         const float* __restrict__ W2r, const float* __restrict__ W2i,
                         float* __restrict__ C, const float* __restrict__ PSUM,
                         const float* __restrict__ bias){
  __shared__ float As[32][132];   // [k][m], padded
  __shared__ float Bs[32][132];   // [k][n], padded
  const int bx = blockIdx.x % nb, by = blockIdx.x / nb;
  const int m0 = by << 7, n0 = bx << 7;
  const int tid = threadIdx.x;
  const int tx = tid & 15, ty = tid >> 4;
  const float* Wr = W0r; const float* Wi = W0i;
  if constexpr (EPI == 0){
    int sec = n0 >> 8;
    Wr = (sec == 0) ? W0r : (sec == 1) ? W1r : W2r;
    Wi = (sec == 0) ? W0i : (sec == 1) ? W1i : W2i;
  }
  const int hn = (n0 >> 7) & 1;
  float acc[8][8];
  #pragma unroll
  for (int i = 0; i < 8; ++i)
    #pragma unroll
    for (int j = 0; j < 8; ++j) acc[i][j] = 0.f;

  for (int kt = 0; kt < 8; ++kt){
    if (kt) __syncthreads();
    #pragma unroll
    for (int i = 0; i < 4; ++i){               // A tile: transpose-scatter
      int c = i*256 + tid;
      int row = c >> 3, k4 = c & 7;
      f32x4 v = *(const f32x4*)&A[(size_t)(m0 + row)*256 + kt*32 + k4*4];
      As[k4*4+0][row] = v.x; As[k4*4+1][row] = v.y;
      As[k4*4+2][row] = v.z; As[k4*4+3][row] = v.w;
    }
    #pragma unroll
    for (int i = 0; i < 4; ++i){               // B tile: on-the-fly Wfull
      int c = i*256 + tid;
      int k = c >> 5, n4 = c & 31;
      int gk = kt*32 + k;
      f32x4 v;
      if constexpr (EPI == 2){
        v = *(const f32x4*)&W0r[(size_t)gk*128 + n4*4];
      } else {
        int hk = gk >> 7, kk = gk & 127;
        const float* src = ((hk ^ hn) == 0) ? Wr : Wi;
        v = *(const f32x4*)&src[(size_t)kk*128 + n4*4];
        if (hk == 1 && hn == 0){ v.x = -v.x; v.y = -v.y; v.z = -v.z; v.w = -v.w; }
      }
      *(f32x4*)&Bs[k][n4*4] = v;
    }
    __syncthreads();
    #pragma unroll 8
    for (int k = 0; k < 32; ++k){
      float a[8], b[8];
      *(f32x4*)&a[0] = *(const f32x4*)&As[k][ty*8];
      *(f32x4*)&a[4] = *(const f32x4*)&As[k][ty*8 + 4];
      *(f32x4*)&b[0] = *(const f32x4*)&Bs[k][tx*8];
      *(f32x4*)&b[4] = *(const f32x4*)&Bs[k][tx*8 + 4];
      #pragma unroll
      for (int i = 0; i < 8; ++i)
        #pragma unroll
        for (int j = 0; j < 8; ++j) acc[i][j] += a[i]*b[j];
    }
  }
  #pragma unroll
  for (int i = 0; i < 8; ++i){
    const int row = m0 + ty*8 + i;
    const int col = n0 + tx*8;
    if constexpr (EPI == 0){
      *(f32x4*)&C[(size_t)row*768 + col]     = *(const f32x4*)&acc[i][0];
      *(f32x4*)&C[(size_t)row*768 + col + 4] = *(const f32x4*)&acc[i][4];
    } else if constexpr (EPI == 1){
      const float s = 0.1f * PSUM[row];
      f32x4 z0 = *(const f32x4*)&C[(size_t)row*256 + col];
      f32x4 z1 = *(const f32x4*)&C[(size_t)row*256 + col + 4];
      z0.x += s*acc[i][0]; z0.y += s*acc[i][1]; z0.z += s*acc[i][2]; z0.w += s*acc[i][3];
      z1.x += s*acc[i][4]; z1.y += s*acc[i][5]; z1.z += s*acc[i][6]; z1.w += s*acc[i][7];
      *(f32x4*)&C[(size_t)row*256 + col]     = z0;
      *(f32x4*)&C[(size_t)row*256 + col + 4] = z1;
    } else {
      f32x4 b0 = *(const f32x4*)&bias[col];
      f32x4 b1 = *(const f32x4*)&bias[col + 4];
      f32x4 o0 = {acc[i][0]+b0.x, acc[i][1]+b0.y, acc[i][2]+b0.z, acc[i][3]+b0.w};
      f32x4 o1 = {acc[i][4]+b1.x, acc[i][5]+b1.y, acc[i][6]+b1.z, acc[i][7]+b1.w};
      *(f32x4*)&C[(size_t)row*128 + col]     = o0;
      *(f32x4*)&C[(size_t)row*128 + col + 4] = o1;
    }
  }
}

// ---------------- fp32 flash attention v4: GEMM-style register tiles --------
// 256 thr (tx = tid&31 -> keys/dims, ty = tid>>5 -> 4 q-rows each), 32 q-rows
// per block, grid 256. k-tiles of 128 keys:
//   S-GEMM: 8 chunks of 32 d; a = QTc broadcast f32x4 (4 rows), b = KT f32x4
//           (4 keys) -> 16 FMA / 2 LDS reads.
//   softmax: rows across 32 consecutive lanes, shfl_xor 1..16 (in-wave).
//   PV: P from LDS (f32x4 = 4 keys, broadcast), V natural in 16-key chunks;
//       per 4-key group: 12 reads -> 512 FMA.
// Gate/Mm/PSUM fused into epilogue. LDS = 4.6K + 17.4K (KT|Vs alias) + 16.9K
// = 38.9 KB -> 4 blocks/CU by LDS; launch_bounds(256,3) caps VGPR ~170.
__launch_bounds__(256, 3)
__global__ void k_attn32(const float* __restrict__ QKV, float* __restrict__ ZF,
                         float* __restrict__ Mm, float* __restrict__ PSUM,
                         const float* __restrict__ Wc, const float* __restrict__ bc){
  __shared__ float QTc[32][36];    // Q chunk transposed [d][row], stride 36
  __shared__ float KV[4352];       // KT [d][key] stride 136  |  Vs [key][d] stride 260
  __shared__ float Ps[32][132];    // P [row][key], stride 132
  const int tid = threadIdx.x;
  const int tx = tid & 31;
  const int ty = tid >> 5;
  const int batch = blockIdx.x >> 5, qt = blockIdx.x & 31;
  const int nbase = batch*1024 + qt*32;
  const int kv0 = batch*1024;

  float O[4][8];
  #pragma unroll
  for (int r = 0; r < 4; ++r)
    #pragma unroll
    for (int j = 0; j < 8; ++j) O[r][j] = 0.f;
  float mr[4] = {-3.0e30f, -3.0e30f, -3.0e30f, -3.0e30f};
  float lr[4] = {0.f, 0.f, 0.f, 0.f};

  const int qrow = tid & 31, qd4 = tid >> 5;         // QTc staging map
  const int kkey = tid & 127, kdh = (tid >> 7)*4;    // KT staging map

  for (int t = 0; t < 8; ++t){
    const int kb = kv0 + t*128;
    float S[4][4];
    #pragma unroll
    for (int r = 0; r < 4; ++r)
      #pragma unroll
      for (int e = 0; e < 4; ++e) S[r][e] = 0.f;

    for (int dc = 0; dc < 8; ++dc){
      __syncthreads();                               // prev KV/QTc reads done
      {                                              // stage Q chunk transposed
        f32x4 v = *(const f32x4*)&QKV[(size_t)(nbase + qrow)*768 + dc*32 + qd4*4];
        QTc[qd4*4+0][qrow] = v.x; QTc[qd4*4+1][qrow] = v.y;
        QTc[qd4*4+2][qrow] = v.z; QTc[qd4*4+3][qrow] = v.w;
      }
      #pragma unroll
      for (int i = 0; i < 4; ++i){                   // stage K chunk transposed
        const int d4 = kdh + i;
        f32x4 v = *(const f32x4*)&QKV[(size_t)(kb + kkey)*768 + 256 + dc*32 + d4*4];
        KV[(d4*4+0)*136 + kkey] = v.x; KV[(d4*4+1)*136 + kkey] = v.y;
        KV[(d4*4+2)*136 + kkey] = v.z; KV[(d4*4+3)*136 + kkey] = v.w;
      }
      __syncthreads();
      #pragma unroll 8
      for (int k = 0; k < 32; ++k){
        const f32x4 a = *(const f32x4*)&QTc[k][ty*4];
        const f32x4 b = *(const f32x4*)&KV[k*136 + tx*4];
        S[0][0] += a.x*b.x; S[0][1] += a.x*b.y; S[0][2] += a.x*b.z; S[0][3] += a.x*b.w;
        S[1][0] += a.y*b.x; S[1][1] += a.y*b.y; S[1][2] += a.y*b.z; S[1][3] += a.y*b.w;
        S[2][0] += a.z*b.x; S[2][1] += a.z*b.y; S[2][2] += a.z*b.z; S[2][3] += a.z*b.w;
        S[3][0] += a.w*b.x; S[3][1] += a.w*b.y; S[3][2] += a.w*b.z; S[3][3] += a.w*b.w;
      }
    }
    // ---- online softmax per row (keys of a row live on 32 consecutive lanes)
    float pp[4][4];
    #pragma unroll
    for (int r = 0; r < 4; ++r){
      #pragma unroll
      for (int e = 0; e < 4; ++e) S[r][e] *= QK_SCALE;
      float tm = fmaxf(fmaxf(S[r][0], S[r][1]), fmaxf(S[r][2], S[r][3]));
      tm = fmaxf(tm, __shfl_xor(tm, 1));
      tm = fmaxf(tm, __shfl_xor(tm, 2));
      tm = fmaxf(tm, __shfl_xor(tm, 4));
      tm = fmaxf(tm, __shfl_xor(tm, 8));
      tm = fmaxf(tm, __shfl_xor(tm, 16));
      const float mn = fmaxf(mr[r], tm);
      const float al = expf(mr[r] - mn);
      float rs = 0.f;
      #pragma unroll
      for (int e = 0; e < 4; ++e){ pp[r][e] = expf(S[r][e] - mn); rs += pp[r][e]; }
      rs += __shfl_xor(rs, 1); rs += __shfl_xor(rs, 2);
      rs += __shfl_xor(rs, 4); rs += __shfl_xor(rs, 8);
      rs += __shfl_xor(rs, 16);
      lr[r] = lr[r]*al + rs;
      mr[r] = mn;
      #pragma unroll
      for (int j = 0; j < 8; ++j) O[r][j] *= al;
    }
    #pragma unroll
    for (int r = 0; r < 4; ++r){                     // P -> LDS [row][key]
      f32x4 w = {pp[r][0], pp[r][1], pp[r][2], pp[r][3]};
      *(f32x4*)&Ps[ty*4 + r][tx*4] = w;
    }
    __syncthreads();                                 // P visible; KT reads done

    // ---- PV over 8 chunks of 16 keys ----
    for (int ks = 0; ks < 8; ++ks){
      if (ks) __syncthreads();
      #pragma unroll
      for (int i = 0; i < 4; ++i){                   // stage V chunk natural
        const int c = i*256 + tid;
        const int key = c >> 6, d4 = c & 63;
        *(f32x4*)&KV[key*260 + d4*4] =
            *(const f32x4*)&QKV[(size_t)(kb + ks*16 + key)*768 + 512 + d4*4];
      }
      __syncthreads();
      #pragma unroll
      for (int kg = 0; kg < 4; ++kg){
        const f32x4 P0 = *(const f32x4*)&Ps[ty*4+0][ks*16 + kg*4];
        const f32x4 P1 = *(const f32x4*)&Ps[ty*4+1][ks*16 + kg*4];
        const f32x4 P2 = *(const f32x4*)&Ps[ty*4+2][ks*16 + kg*4];
        const f32x4 P3 = *(const f32x4*)&Ps[ty*4+3][ks*16 + kg*4];
        #pragma unroll
        for (int k2 = 0; k2 < 4; ++k2){
          const f32x4 v0 = *(const f32x4*)&KV[(kg*4+k2)*260 + tx*8];
          const f32x4 v1 = *(const f32x4*)&KV[(kg*4+k2)*260 + tx*8 + 4];
          const float a0 = P0[k2], a1 = P1[k2], a2 = P2[k2], a3 = P3[k2];
          O[0][0] += a0*v0.x; O[0][1] += a0*v0.y; O[0][2] += a0*v0.z; O[0][3] += a0*v0.w;
          O[0][4] += a0*v1.x; O[0][5] += a0*v1.y; O[0][6] += a0*v1.z; O[0][7] += a0*v1.w;
          O[1][0] += a1*v0.x; O[1][1] += a1*v0.y; O[1][2] += a1*v0.z; O[1][3] += a1*v0.w;
          O[1][4] += a1*v1.x; O[1][5] += a1*v1.y; O[1][6] += a1*v1.z; O[1][7] += a1*v1.w;
          O[2][0] += a2*v0.x; O[2][1] += a2*v0.y; O[2][2] += a2*v0.z; O[2][3] += a2*v0.w;
          O[2][4] += a2*v1.x; O[2][5] += a2*v1.y; O[2][6] += a2*v1.z; O[2][7] += a2*v1.w;
          O[3][0] += a3*v0.x; O[3][1] += a3*v0.y; O[3][2] += a3*v0.z; O[3][3] += a3*v0.w;
          O[3][4] += a3*v1.x; O[3][5] += a3*v1.y; O[3][6] += a3*v1.z; O[3][7] += a3*v1.w;
        }
      }
    }
  }
  // ---- epilogue: normalize + fused gate + memory/pointer update ----
  const float bc0 = bc[0], bc1 = bc[1], bc2 = bc[2];
  #pragma unroll
  for (int r = 0; r < 4; ++r){
    const float inv = 1.f / lr[r];
    #pragma unroll
    for (int j = 0; j < 8; ++j) O[r][j] *= inv;
    float d0 = 0.f, d1 = 0.f, d2 = 0.f;
    #pragma unroll
    for (int j = 0; j < 8; ++j){
      const int dim = tx*8 + j;
      const float z = O[r][j];
      d0 += z*Wc[dim*3 + 0]; d1 += z*Wc[dim*3 + 1]; d2 += z*Wc[dim*3 + 2];
    }
    d0 += __shfl_xor(d0,1); d0 += __shfl_xor(d0,2); d0 += __shfl_xor(d0,4);
    d0 += __shfl_xor(d0,8); d0 += __shfl_xor(d0,16);
    d1 += __shfl_xor(d1,1); d1 += __shfl_xor(d1,2); d1 += __shfl_xor(d1,4);
    d1 += __shfl_xor(d1,8); d1 += __shfl_xor(d1,16);
    d2 += __shfl_xor(d2,1); d2 += __shfl_xor(d2,2); d2 += __shfl_xor(d2,4);
    d2 += __shfl_xor(d2,8); d2 += __shfl_xor(d2,16);
    const float g0 = 1.f/(1.f + expf(-(d0 + bc0)));
    const float g1 = 1.f/(1.f + expf(-(d1 + bc1)));
    const float g2 = 1.f/(1.f + expf(-(d2 + bc2)));
    const float tt = g0 + g1 + g2, tot = tt + 1e-6f;
    const float push = g0/tot;
    const int row = nbase + ty*4 + r;
    if (tx == 0) PSUM[row] *= tt/tot;
    const size_t idx = (size_t)row*256 + tx*8;
    f32x4 z0 = {O[r][0], O[r][1], O[r][2], O[r][3]};
    f32x4 z1 = {O[r][4], O[r][5], O[r][6], O[r][7]};
    f32x4 m0 = *(const f32x4*)&Mm[idx];
    f32x4 m1 = *(const f32x4*)&Mm[idx + 4];
    m0.x += push*(z0.x - m0.x); m0.y += push*(z0.y - m0.y);
    m0.z += push*(z0.z - m0.z); m0.w += push*(z0.w - m0.w);
    m1.x += push*(z1.x - m1.x); m1.y += push*(z1.y - m1.y);
    m1.z += push*(z1.z - m1.z); m1.w += push*(z1.w - m1.w);
    *(f32x4*)&Mm[idx]     = m0;
    *(f32x4*)&Mm[idx + 4] = m1;
    *(f32x4*)&ZF[idx]     = z0;
    *(f32x4*)&ZF[idx + 4] = z1;
  }
}

// ---------------------------------------------------------------------------
extern "C" void kernel_launch(void* const* d_in, const int* in_sizes, int n_in,
                              void* d_out, int out_size, void* d_ws, size_t ws_size,
                              hipStream_t stream){
  (void)in_sizes; (void)n_in; (void)out_size; (void)ws_size;
  const float* xr   = (const float*)d_in[0];
  const float* xi   = (const float*)d_in[1];
  const float* Wq_r = (const float*)d_in[2];
  const float* Wq_i = (const float*)d_in[3];
  const float* Wk_r = (const float*)d_in[4];
  const float* Wk_i = (const float*)d_in[5];
  const float* Wv_r = (const float*)d_in[6];
  const float* Wv_i = (const float*)d_in[7];
  // d_in[8..11] (Mq_*, Mk_*) unused: all stack slots identical -> memory
  // attention exactly uniform regardless of its q/k projections (verified r3).
  const float* Mv_r = (const float*)d_in[12];
  const float* Mv_i = (const float*)d_in[13];
  const float* Wc   = (const float*)d_in[14];
  const float* bc   = (const float*)d_in[15];
  const float* Wo   = (const float*)d_in[16];
  const float* bo   = (const float*)d_in[17];

  // Workspace layout identical to verified round 3/6 (41,975,808 B).
  uint8_t* w = (uint8_t*)d_ws;
  float* Z    = (float*)w; w += (size_t)8192*256*4;   // state; aliased as ZF
  float* QKV  = (float*)w; w += (size_t)8192*768*4;
  float* Mm   = (float*)w; w += (size_t)8192*256*4;
  float* PSUM = (float*)w; w += (size_t)8192*4;
  float* ZF   = Z;  // safe alias: state dead once proj consumed it.

  k_init32<<<dim3(1024), dim3(256), 0, stream>>>(xr, xi, Z, Mm, PSUM);
  for (int t = 0; t < 8; ++t){
    k_gemm32<0><<<dim3(384), dim3(256), 0, stream>>>(Z, 6,
        Wq_r, Wq_i, Wk_r, Wk_i, Wv_r, Wv_i, QKV, nullptr, nullptr);
    k_attn32<<<dim3(256), dim3(256), 0, stream>>>(QKV, ZF, Mm, PSUM, Wc, bc);
    k_gemm32<1><<<dim3(128), dim3(256), 0, stream>>>(Mm, 2,
        Mv_r, Mv_i, nullptr, nullptr, nullptr, nullptr, Z, PSUM, nullptr);
  }
  k_gemm32<2><<<dim3(64), dim3(256), 0, stream>>>(Z, 1,
      Wo, nullptr, nullptr, nullptr, nullptr, nullptr, (float*)d_out, nullptr, bo);
}

// Round 12
// 2502.937 us; speedup vs baseline: 2.5864x; 1.2792x over previous
//
#include <hip/hip_runtime.h>
#include <stdint.h>

typedef __attribute__((ext_vector_type(4))) float f32x4;

constexpr float QK_SCALE = 0.08838834764831845f;  // 128^-0.5

// ===========================================================================
// All-fp32 pipeline (bf16 numerically forbidden: 8-step recursion amplifies
// per-step noise ~1e3-1e4; verified r3-r5). Graph identical to verified r3.
// Stack-memory collapse (verified r3): all K slots identical -> uniform
// memory attention -> Mq/Mk unused; read = PSUM * (Mm @ Mv_full).
// r11 lesson (measured): 4x4 register tiles fixed intensity (conflicts ~4%),
// but grid 256 x 4 waves = 1 wave/SIMD (Occ 11.5%, VALUBusy 23%) -> stalls
// unhidden. This round: same tiles, 512-thr blocks (8 waves co-op on one
// 32-row x 256-key tile) -> 2 waves/SIMD, row == wave for softmax.
// ===========================================================================

__global__ void k_init32(const float* __restrict__ xr, const float* __restrict__ xi,
                         float* __restrict__ Z, float* __restrict__ Mm,
                         float* __restrict__ PSUM){
  for (int i = blockIdx.x*blockDim.x + threadIdx.x; i < 8192*256; i += gridDim.x*blockDim.x){
    int n = i >> 8, d = i & 255;
    Z[i]  = (d < 128) ? xr[n*128 + d] : xi[n*128 + d - 128];
    Mm[i] = 0.f;
    if (i < 8192) PSUM[i] = 1.f;
  }
}

// ---------------- tiled fp32 GEMM (unchanged from verified r6) --------------
template<int EPI>
__launch_bounds__(256, 2)
__global__ void k_gemm32(const float* __restrict__ A, int nb,
                         const float* __restrict__ W0r, const float* __restrict__ W0i,
                         const float* __restrict__ W1r, const float* __restrict__ W1i,
                         const float* __restrict__ W2r, const float* __restrict__ W2i,
                         float* __restrict__ C, const float* __restrict__ PSUM,
                         const float* __restrict__ bias){
  __shared__ float As[32][132];   // [k][m], padded
  __shared__ float Bs[32][132];   // [k][n], padded
  const int bx = blockIdx.x % nb, by = blockIdx.x / nb;
  const int m0 = by << 7, n0 = bx << 7;
  const int tid = threadIdx.x;
  const int tx = tid & 15, ty = tid >> 4;
  const float* Wr = W0r; const float* Wi = W0i;
  if constexpr (EPI == 0){
    int sec = n0 >> 8;
    Wr = (sec == 0) ? W0r : (sec == 1) ? W1r : W2r;
    Wi = (sec == 0) ? W0i : (sec == 1) ? W1i : W2i;
  }
  const int hn = (n0 >> 7) & 1;
  float acc[8][8];
  #pragma unroll
  for (int i = 0; i < 8; ++i)
    #pragma unroll
    for (int j = 0; j < 8; ++j) acc[i][j] = 0.f;

  for (int kt = 0; kt < 8; ++kt){
    if (kt) __syncthreads();
    #pragma unroll
    for (int i = 0; i < 4; ++i){               // A tile: transpose-scatter
      int c = i*256 + tid;
      int row = c >> 3, k4 = c & 7;
      f32x4 v = *(const f32x4*)&A[(size_t)(m0 + row)*256 + kt*32 + k4*4];
      As[k4*4+0][row] = v.x; As[k4*4+1][row] = v.y;
      As[k4*4+2][row] = v.z; As[k4*4+3][row] = v.w;
    }
    #pragma unroll
    for (int i = 0; i < 4; ++i){               // B tile: on-the-fly Wfull
      int c = i*256 + tid;
      int k = c >> 5, n4 = c & 31;
      int gk = kt*32 + k;
      f32x4 v;
      if constexpr (EPI == 2){
        v = *(const f32x4*)&W0r[(size_t)gk*128 + n4*4];
      } else {
        int hk = gk >> 7, kk = gk & 127;
        const float* src = ((hk ^ hn) == 0) ? Wr : Wi;
        v = *(const f32x4*)&src[(size_t)kk*128 + n4*4];
        if (hk == 1 && hn == 0){ v.x = -v.x; v.y = -v.y; v.z = -v.z; v.w = -v.w; }
      }
      *(f32x4*)&Bs[k][n4*4] = v;
    }
    __syncthreads();
    #pragma unroll 8
    for (int k = 0; k < 32; ++k){
      float a[8], b[8];
      *(f32x4*)&a[0] = *(const f32x4*)&As[k][ty*8];
      *(f32x4*)&a[4] = *(const f32x4*)&As[k][ty*8 + 4];
      *(f32x4*)&b[0] = *(const f32x4*)&Bs[k][tx*8];
      *(f32x4*)&b[4] = *(const f32x4*)&Bs[k][tx*8 + 4];
      #pragma unroll
      for (int i = 0; i < 8; ++i)
        #pragma unroll
        for (int j = 0; j < 8; ++j) acc[i][j] += a[i]*b[j];
    }
  }
  #pragma unroll
  for (int i = 0; i < 8; ++i){
    const int row = m0 + ty*8 + i;
    const int col = n0 + tx*8;
    if constexpr (EPI == 0){
      *(f32x4*)&C[(size_t)row*768 + col]     = *(const f32x4*)&acc[i][0];
      *(f32x4*)&C[(size_t)row*768 + col + 4] = *(const f32x4*)&acc[i][4];
    } else if constexpr (EPI == 1){
      const float s = 0.1f * PSUM[row];
      f32x4 z0 = *(const f32x4*)&C[(size_t)row*256 + col];
      f32x4 z1 = *(const f32x4*)&C[(size_t)row*256 + col + 4];
      z0.x += s*acc[i][0]; z0.y += s*acc[i][1]; z0.z += s*acc[i][2]; z0.w += s*acc[i][3];
      z1.x += s*acc[i][4]; z1.y += s*acc[i][5]; z1.z += s*acc[i][6]; z1.w += s*acc[i][7];
      *(f32x4*)&C[(size_t)row*256 + col]     = z0;
      *(f32x4*)&C[(size_t)row*256 + col + 4] = z1;
    } else {
      f32x4 b0 = *(const f32x4*)&bias[col];
      f32x4 b1 = *(const f32x4*)&bias[col + 4];
      f32x4 o0 = {acc[i][0]+b0.x, acc[i][1]+b0.y, acc[i][2]+b0.z, acc[i][3]+b0.w};
      f32x4 o1 = {acc[i][4]+b1.x, acc[i][5]+b1.y, acc[i][6]+b1.z, acc[i][7]+b1.w};
      *(f32x4*)&C[(size_t)row*128 + col]     = o0;
      *(f32x4*)&C[(size_t)row*128 + col + 4] = o1;
    }
  }
}

// ---------------- fp32 flash attention v5: 8 waves, row == wave -------------
// 512 thr: ty = tid>>6 (wave, 4 q-rows: ty*4+r), tx = tid&63 (4 keys / 4 dims).
// 32 q-rows x 256-key tiles, grid 256. QK: 16-d chunks, a = QTc f32x4
// broadcast, b = KT f32x4 -> 16 FMA / 2 reads. Softmax: full-wave 6-step
// shfl_xor (row lives on exactly one wave). P -> per-row LDS strip (own wave
// only: no barrier). PV: 16-key V chunks, 16 FMA / v-read. Gate fused.
// LDS = 2.3K + 16.6K + 33.3K = 52.2K. Strides 260 (16B-aligned b128).
__launch_bounds__(512, 1)
__global__ void k_attn32(const float* __restrict__ QKV, float* __restrict__ ZF,
                         float* __restrict__ Mm, float* __restrict__ PSUM,
                         const float* __restrict__ Wc, const float* __restrict__ bc){
  __shared__ __align__(16) float QTc[16][36];   // Q chunk transposed [d][row]
  __shared__ __align__(16) float KV[16*260];    // KT [d][key] | V [key][d]
  __shared__ __align__(16) float Ps[32*260];    // P [row][key]
  const int tid = threadIdx.x;
  const int tx = tid & 63;
  const int ty = tid >> 6;
  const int batch = blockIdx.x >> 5, qt = blockIdx.x & 31;
  const int nbase = batch*1024 + qt*32;
  const int kv0 = batch*1024;

  float O[4][4];
  #pragma unroll
  for (int r = 0; r < 4; ++r)
    #pragma unroll
    for (int j = 0; j < 4; ++j) O[r][j] = 0.f;
  float mr[4] = {-3.0e30f, -3.0e30f, -3.0e30f, -3.0e30f};
  float lr[4] = {0.f, 0.f, 0.f, 0.f};

  const int qq = tid & 31, qd = tid >> 5;       // QTc staging map (512 slots)

  for (int t = 0; t < 4; ++t){
    const int kb = kv0 + t*256;
    float S[4][4];
    #pragma unroll
    for (int r = 0; r < 4; ++r)
      #pragma unroll
      for (int e = 0; e < 4; ++e) S[r][e] = 0.f;

    for (int dc = 0; dc < 16; ++dc){
      __syncthreads();                          // KV/QTc safe to overwrite
      QTc[qd][qq] = QKV[(size_t)(nbase + qq)*768 + dc*16 + qd];
      #pragma unroll
      for (int i = 0; i < 2; ++i){              // stage K chunk transposed
        const int c = i*512 + tid;
        const int key = c & 255, d4 = c >> 8;
        f32x4 v = *(const f32x4*)&QKV[(size_t)(kb + key)*768 + 256 + dc*16 + d4*4];
        KV[(d4*4+0)*260 + key] = v.x; KV[(d4*4+1)*260 + key] = v.y;
        KV[(d4*4+2)*260 + key] = v.z; KV[(d4*4+3)*260 + key] = v.w;
      }
      __syncthreads();
      #pragma unroll
      for (int k = 0; k < 16; ++k){
        const f32x4 a = *(const f32x4*)&QTc[k][ty*4];
        const f32x4 b = *(const f32x4*)&KV[k*260 + tx*4];
        S[0][0] += a.x*b.x; S[0][1] += a.x*b.y; S[0][2] += a.x*b.z; S[0][3] += a.x*b.w;
        S[1][0] += a.y*b.x; S[1][1] += a.y*b.y; S[1][2] += a.y*b.z; S[1][3] += a.y*b.w;
        S[2][0] += a.z*b.x; S[2][1] += a.z*b.y; S[2][2] += a.z*b.z; S[2][3] += a.z*b.w;
        S[3][0] += a.w*b.x; S[3][1] += a.w*b.y; S[3][2] += a.w*b.z; S[3][3] += a.w*b.w;
      }
    }
    // ---- online softmax: row = wave, reduce across all 64 lanes ----
    #pragma unroll
    for (int r = 0; r < 4; ++r){
      #pragma unroll
      for (int e = 0; e < 4; ++e) S[r][e] *= QK_SCALE;
      float tm = fmaxf(fmaxf(S[r][0], S[r][1]), fmaxf(S[r][2], S[r][3]));
      tm = fmaxf(tm, __shfl_xor(tm, 1));
      tm = fmaxf(tm, __shfl_xor(tm, 2));
      tm = fmaxf(tm, __shfl_xor(tm, 4));
      tm = fmaxf(tm, __shfl_xor(tm, 8));
      tm = fmaxf(tm, __shfl_xor(tm, 16));
      tm = fmaxf(tm, __shfl_xor(tm, 32));
      const float mn = fmaxf(mr[r], tm);
      const float al = expf(mr[r] - mn);
      float p0 = expf(S[r][0] - mn), p1 = expf(S[r][1] - mn);
      float p2 = expf(S[r][2] - mn), p3 = expf(S[r][3] - mn);
      float rs = (p0 + p1) + (p2 + p3);
      rs += __shfl_xor(rs, 1); rs += __shfl_xor(rs, 2);
      rs += __shfl_xor(rs, 4); rs += __shfl_xor(rs, 8);
      rs += __shfl_xor(rs, 16); rs += __shfl_xor(rs, 32);
      lr[r] = lr[r]*al + rs;
      mr[r] = mn;
      O[r][0] *= al; O[r][1] *= al; O[r][2] *= al; O[r][3] *= al;
      f32x4 w = {p0, p1, p2, p3};
      *(f32x4*)&Ps[(ty*4 + r)*260 + tx*4] = w;  // own wave writes/reads: no barrier
    }
    // ---- PV over 16 chunks of 16 keys ----
    for (int ks = 0; ks < 16; ++ks){
      __syncthreads();                          // KT/prev-V readers done
      #pragma unroll
      for (int i = 0; i < 2; ++i){              // stage V chunk natural
        const int c = i*512 + tid;
        const int key = c >> 6, d4 = c & 63;
        *(f32x4*)&KV[key*260 + d4*4] =
            *(const f32x4*)&QKV[(size_t)(kb + ks*16 + key)*768 + 512 + d4*4];
      }
      __syncthreads();
      #pragma unroll
      for (int kg = 0; kg < 4; ++kg){
        const f32x4 P0 = *(const f32x4*)&Ps[(ty*4+0)*260 + ks*16 + kg*4];
        const f32x4 P1 = *(const f32x4*)&Ps[(ty*4+1)*260 + ks*16 + kg*4];
        const f32x4 P2 = *(const f32x4*)&Ps[(ty*4+2)*260 + ks*16 + kg*4];
        const f32x4 P3 = *(const f32x4*)&Ps[(ty*4+3)*260 + ks*16 + kg*4];
        #pragma unroll
        for (int k2 = 0; k2 < 4; ++k2){
          const f32x4 v = *(const f32x4*)&KV[(kg*4+k2)*260 + tx*4];
          const float a0 = P0[k2], a1 = P1[k2], a2 = P2[k2], a3 = P3[k2];
          O[0][0] += a0*v.x; O[0][1] += a0*v.y; O[0][2] += a0*v.z; O[0][3] += a0*v.w;
          O[1][0] += a1*v.x; O[1][1] += a1*v.y; O[1][2] += a1*v.z; O[1][3] += a1*v.w;
          O[2][0] += a2*v.x; O[2][1] += a2*v.y; O[2][2] += a2*v.z; O[2][3] += a2*v.w;
          O[3][0] += a3*v.x; O[3][1] += a3*v.y; O[3][2] += a3*v.z; O[3][3] += a3*v.w;
        }
      }
    }
  }
  // ---- epilogue: normalize + fused gate + memory/pointer update ----
  const float bc0 = bc[0], bc1 = bc[1], bc2 = bc[2];
  #pragma unroll
  for (int r = 0; r < 4; ++r){
    const float inv = 1.f / lr[r];
    #pragma unroll
    for (int j = 0; j < 4; ++j) O[r][j] *= inv;
    float d0 = 0.f, d1 = 0.f, d2 = 0.f;
    #pragma unroll
    for (int j = 0; j < 4; ++j){
      const int dim = tx*4 + j;
      const float z = O[r][j];
      d0 += z*Wc[dim*3 + 0]; d1 += z*Wc[dim*3 + 1]; d2 += z*Wc[dim*3 + 2];
    }
    d0 += __shfl_xor(d0,1); d0 += __shfl_xor(d0,2); d0 += __shfl_xor(d0,4);
    d0 += __shfl_xor(d0,8); d0 += __shfl_xor(d0,16); d0 += __shfl_xor(d0,32);
    d1 += __shfl_xor(d1,1); d1 += __shfl_xor(d1,2); d1 += __shfl_xor(d1,4);
    d1 += __shfl_xor(d1,8); d1 += __shfl_xor(d1,16); d1 += __shfl_xor(d1,32);
    d2 += __shfl_xor(d2,1); d2 += __shfl_xor(d2,2); d2 += __shfl_xor(d2,4);
    d2 += __shfl_xor(d2,8); d2 += __shfl_xor(d2,16); d2 += __shfl_xor(d2,32);
    const float g0 = 1.f/(1.f + expf(-(d0 + bc0)));
    const float g1 = 1.f/(1.f + expf(-(d1 + bc1)));
    const float g2 = 1.f/(1.f + expf(-(d2 + bc2)));
    const float tt = g0 + g1 + g2, tot = tt + 1e-6f;
    const float push = g0/tot;
    const int row = nbase + ty*4 + r;
    if (tx == 0) PSUM[row] *= tt/tot;
    const size_t idx = (size_t)row*256 + tx*4;
    f32x4 z0 = {O[r][0], O[r][1], O[r][2], O[r][3]};
    f32x4 m0 = *(const f32x4*)&Mm[idx];
    m0.x += push*(z0.x - m0.x); m0.y += push*(z0.y - m0.y);
    m0.z += push*(z0.z - m0.z); m0.w += push*(z0.w - m0.w);
    *(f32x4*)&Mm[idx] = m0;
    *(f32x4*)&ZF[idx] = z0;
  }
}

// ---------------------------------------------------------------------------
extern "C" void kernel_launch(void* const* d_in, const int* in_sizes, int n_in,
                              void* d_out, int out_size, void* d_ws, size_t ws_size,
                              hipStream_t stream){
  (void)in_sizes; (void)n_in; (void)out_size; (void)ws_size;
  const float* xr   = (const float*)d_in[0];
  const float* xi   = (const float*)d_in[1];
  const float* Wq_r = (const float*)d_in[2];
  const float* Wq_i = (const float*)d_in[3];
  const float* Wk_r = (const float*)d_in[4];
  const float* Wk_i = (const float*)d_in[5];
  const float* Wv_r = (const float*)d_in[6];
  const float* Wv_i = (const float*)d_in[7];
  // d_in[8..11] (Mq_*, Mk_*) unused: all stack slots identical -> memory
  // attention exactly uniform regardless of its q/k projections (verified r3).
  const float* Mv_r = (const float*)d_in[12];
  const float* Mv_i = (const float*)d_in[13];
  const float* Wc   = (const float*)d_in[14];
  const float* bc   = (const float*)d_in[15];
  const float* Wo   = (const float*)d_in[16];
  const float* bo   = (const float*)d_in[17];

  // Workspace layout identical to verified round 3/6 (41,975,808 B).
  uint8_t* w = (uint8_t*)d_ws;
  float* Z    = (float*)w; w += (size_t)8192*256*4;   // state; aliased as ZF
  float* QKV  = (float*)w; w += (size_t)8192*768*4;
  float* Mm   = (float*)w; w += (size_t)8192*256*4;
  float* PSUM = (float*)w; w += (size_t)8192*4;
  float* ZF   = Z;  // safe alias: state dead once proj consumed it.

  k_init32<<<dim3(1024), dim3(256), 0, stream>>>(xr, xi, Z, Mm, PSUM);
  for (int t = 0; t < 8; ++t){
    k_gemm32<0><<<dim3(384), dim3(256), 0, stream>>>(Z, 6,
        Wq_r, Wq_i, Wk_r, Wk_i, Wv_r, Wv_i, QKV, nullptr, nullptr);
    k_attn32<<<dim3(256), dim3(512), 0, stream>>>(QKV, ZF, Mm, PSUM, Wc, bc);
    k_gemm32<1><<<dim3(128), dim3(256), 0, stream>>>(Mm, 2,
        Mv_r, Mv_i, nullptr, nullptr, nullptr, nullptr, Z, PSUM, nullptr);
  }
  k_gemm32<2><<<dim3(64), dim3(256), 0, stream>>>(Z, 1,
      Wo, nullptr, nullptr, nullptr, nullptr, nullptr, (float*)d_out, nullptr, bo);
}

// Round 13
// 2113.771 us; speedup vs baseline: 3.0626x; 1.1841x over previous
//
#include <hip/hip_runtime.h>
#include <stdint.h>

typedef __attribute__((ext_vector_type(4))) float f32x4;

constexpr float QK_SCALE = 0.08838834764831845f;  // 128^-0.5

#define DEV static __device__ __forceinline__

DEV float rdl(float v, int l){          // wave-uniform lane read (VALU pipe)
  union { float f; int i; } u; u.f = v;
  u.i = __builtin_amdgcn_readlane(u.i, l);
  return u.f;
}

// ===========================================================================
// All-fp32 pipeline (bf16 numerically forbidden: 8-step recursion amplifies
// per-step noise ~1e3-1e4; verified r3-r5). Graph identical to verified r3.
// Stack-memory collapse (verified r3): all K slots identical -> uniform
// memory attention -> Mq/Mk unused; read = PSUM * (Mm @ Mv_full).
// r12 lesson (measured): attn is LDS-instruction-rate bound (~9.7k LDS ops
// per 256-key tile; VALUBusy 34%). v6 moves Q and P to registers and reads
// them via v_readlane (VALU pipe, uniform index): -A-reads, -P r/w, -Ps
// buffer -> ~5.8k LDS ops/tile. GEMMs: BM=64 tiles for grid balance
// (GEMM<0> 384->768 blocks, GEMM<1> 128->256).
// ===========================================================================

__global__ void k_init32(const float* __restrict__ xr, const float* __restrict__ xi,
                         float* __restrict__ Z, float* __restrict__ Mm,
                         float* __restrict__ PSUM){
  for (int i = blockIdx.x*blockDim.x + threadIdx.x; i < 8192*256; i += gridDim.x*blockDim.x){
    int n = i >> 8, d = i & 255;
    Z[i]  = (d < 128) ? xr[n*128 + d] : xi[n*128 + d - 128];
    Mm[i] = 0.f;
    if (i < 8192) PSUM[i] = 1.f;
  }
}

// ---------------- tiled fp32 GEMM (r6 core, BM templated for balance) -------
template<int EPI, int BM>
__launch_bounds__(256, 2)
__global__ void k_gemm32(const float* __restrict__ A, int nb,
                         const float* __restrict__ W0r, const float* __restrict__ W0i,
                         const float* __restrict__ W1r, const float* __restrict__ W1i,
                         const float* __restrict__ W2r, const float* __restrict__ W2i,
                         float* __restrict__ C, const float* __restrict__ PSUM,
                         const float* __restrict__ bias){
  constexpr int RM = BM / 16;               // rows per thread
  __shared__ float As[32][BM + 4];          // [k][m], padded
  __shared__ float Bs[32][132];             // [k][n], padded
  const int bx = blockIdx.x % nb, by = blockIdx.x / nb;
  const int m0 = by * BM, n0 = bx << 7;
  const int tid = threadIdx.x;
  const int tx = tid & 15, ty = tid >> 4;
  const float* Wr = W0r; const float* Wi = W0i;
  if constexpr (EPI == 0){
    int sec = n0 >> 8;
    Wr = (sec == 0) ? W0r : (sec == 1) ? W1r : W2r;
    Wi = (sec == 0) ? W0i : (sec == 1) ? W1i : W2i;
  }
  const int hn = (n0 >> 7) & 1;
  float acc[RM][8];
  #pragma unroll
  for (int i = 0; i < RM; ++i)
    #pragma unroll
    for (int j = 0; j < 8; ++j) acc[i][j] = 0.f;

  for (int kt = 0; kt < 8; ++kt){
    if (kt) __syncthreads();
    #pragma unroll
    for (int i = 0; i < BM/32; ++i){           // A tile: transpose-scatter
      int c = i*256 + tid;                     // < BM*8 f32x4 units
      int row = c >> 3, k4 = c & 7;
      f32x4 v = *(const f32x4*)&A[(size_t)(m0 + row)*256 + kt*32 + k4*4];
      As[k4*4+0][row] = v.x; As[k4*4+1][row] = v.y;
      As[k4*4+2][row] = v.z; As[k4*4+3][row] = v.w;
    }
    #pragma unroll
    for (int i = 0; i < 4; ++i){               // B tile: on-the-fly Wfull
      int c = i*256 + tid;
      int k = c >> 5, n4 = c & 31;
      int gk = kt*32 + k;
      f32x4 v;
      if constexpr (EPI == 2){
        v = *(const f32x4*)&W0r[(size_t)gk*128 + n4*4];
      } else {
        int hk = gk >> 7, kk = gk & 127;
        const float* src = ((hk ^ hn) == 0) ? Wr : Wi;
        v = *(const f32x4*)&src[(size_t)kk*128 + n4*4];
        if (hk == 1 && hn == 0){ v.x = -v.x; v.y = -v.y; v.z = -v.z; v.w = -v.w; }
      }
      *(f32x4*)&Bs[k][n4*4] = v;
    }
    __syncthreads();
    #pragma unroll 8
    for (int k = 0; k < 32; ++k){
      float a[RM], b[8];
      #pragma unroll
      for (int i4 = 0; i4 < RM/4; ++i4)
        *(f32x4*)&a[i4*4] = *(const f32x4*)&As[k][ty*RM + i4*4];
      *(f32x4*)&b[0] = *(const f32x4*)&Bs[k][tx*8];
      *(f32x4*)&b[4] = *(const f32x4*)&Bs[k][tx*8 + 4];
      #pragma unroll
      for (int i = 0; i < RM; ++i)
        #pragma unroll
        for (int j = 0; j < 8; ++j) acc[i][j] += a[i]*b[j];
    }
  }
  #pragma unroll
  for (int i = 0; i < RM; ++i){
    const int row = m0 + ty*RM + i;
    const int col = n0 + tx*8;
    if constexpr (EPI == 0){
      *(f32x4*)&C[(size_t)row*768 + col]     = *(const f32x4*)&acc[i][0];
      *(f32x4*)&C[(size_t)row*768 + col + 4] = *(const f32x4*)&acc[i][4];
    } else if constexpr (EPI == 1){
      const float s = 0.1f * PSUM[row];
      f32x4 z0 = *(const f32x4*)&C[(size_t)row*256 + col];
      f32x4 z1 = *(const f32x4*)&C[(size_t)row*256 + col + 4];
      z0.x += s*acc[i][0]; z0.y += s*acc[i][1]; z0.z += s*acc[i][2]; z0.w += s*acc[i][3];
      z1.x += s*acc[i][4]; z1.y += s*acc[i][5]; z1.z += s*acc[i][6]; z1.w += s*acc[i][7];
      *(f32x4*)&C[(size_t)row*256 + col]     = z0;
      *(f32x4*)&C[(size_t)row*256 + col + 4] = z1;
    } else {
      f32x4 b0 = *(const f32x4*)&bias[col];
      f32x4 b1 = *(const f32x4*)&bias[col + 4];
      f32x4 o0 = {acc[i][0]+b0.x, acc[i][1]+b0.y, acc[i][2]+b0.z, acc[i][3]+b0.w};
      f32x4 o1 = {acc[i][4]+b1.x, acc[i][5]+b1.y, acc[i][6]+b1.z, acc[i][7]+b1.w};
      *(f32x4*)&C[(size_t)row*128 + col]     = o0;
      *(f32x4*)&C[(size_t)row*128 + col + 4] = o1;
    }
  }
}

// ---------------- fp32 flash attention v6: Q,P in registers + readlane ------
// 512 thr: ty = tid>>6 (wave, rows ty*4..+3), tx = tid&63 (4 keys / 4 dims).
// Q lane-distributed: qreg[r][g] = Q[row][g*64 + lane] (loaded once).
// QK: K staged transposed (r12, conflict-free); A-operand via v_readlane
// (VALU pipe) -> no LDS A-reads. Softmax P stays in registers (lane tx owns
// keys tx*4..+3); PV fetches P via readlane(pp[r][k2], ks*4+kg).
// LDS = one 16.6 KB K/V chunk buffer only. Gate fused (r12-verified).
__launch_bounds__(512, 1)
__global__ void k_attn32(const float* __restrict__ QKV, float* __restrict__ ZF,
                         float* __restrict__ Mm, float* __restrict__ PSUM,
                         const float* __restrict__ Wc, const float* __restrict__ bc){
  __shared__ __align__(16) float KV[16*260];    // KT [d][key] | V [key][d]
  const int tid = threadIdx.x;
  const int tx = tid & 63;
  const int ty = tid >> 6;
  const int batch = blockIdx.x >> 5, qt = blockIdx.x & 31;
  const int nbase = batch*1024 + qt*32;
  const int kv0 = batch*1024;

  float qreg[4][4];                             // Q[row ty*4+r][g*64 + lane]
  #pragma unroll
  for (int r = 0; r < 4; ++r)
    #pragma unroll
    for (int g = 0; g < 4; ++g)
      qreg[r][g] = QKV[(size_t)(nbase + ty*4 + r)*768 + g*64 + tx];

  float O[4][4];
  #pragma unroll
  for (int r = 0; r < 4; ++r)
    #pragma unroll
    for (int j = 0; j < 4; ++j) O[r][j] = 0.f;
  float mr[4] = {-3.0e30f, -3.0e30f, -3.0e30f, -3.0e30f};
  float lr[4] = {0.f, 0.f, 0.f, 0.f};

  for (int t = 0; t < 4; ++t){
    const int kb = kv0 + t*256;
    float S[4][4];
    #pragma unroll
    for (int r = 0; r < 4; ++r)
      #pragma unroll
      for (int e = 0; e < 4; ++e) S[r][e] = 0.f;

    #pragma unroll
    for (int gg = 0; gg < 4; ++gg){             // qreg g-index compile-time
      for (int dcc = 0; dcc < 4; ++dcc){        // runtime: bounds reg pressure
        const int dc = gg*4 + dcc;
        __syncthreads();                        // prev chunk readers done
        #pragma unroll
        for (int i = 0; i < 2; ++i){            // stage K chunk transposed
          const int c = i*512 + tid;
          const int key = c & 255, d4 = c >> 8;
          f32x4 v = *(const f32x4*)&QKV[(size_t)(kb + key)*768 + 256 + dc*16 + d4*4];
          KV[(d4*4+0)*260 + key] = v.x; KV[(d4*4+1)*260 + key] = v.y;
          KV[(d4*4+2)*260 + key] = v.z; KV[(d4*4+3)*260 + key] = v.w;
        }
        __syncthreads();
        #pragma unroll
        for (int k = 0; k < 16; ++k){
          const int ln = dcc*16 + k;            // (dc*16+k)&63, uniform
          const float a0 = rdl(qreg[0][gg], ln);
          const float a1 = rdl(qreg[1][gg], ln);
          const float a2 = rdl(qreg[2][gg], ln);
          const float a3 = rdl(qreg[3][gg], ln);
          const f32x4 b = *(const f32x4*)&KV[k*260 + tx*4];
          S[0][0] += a0*b.x; S[0][1] += a0*b.y; S[0][2] += a0*b.z; S[0][3] += a0*b.w;
          S[1][0] += a1*b.x; S[1][1] += a1*b.y; S[1][2] += a1*b.z; S[1][3] += a1*b.w;
          S[2][0] += a2*b.x; S[2][1] += a2*b.y; S[2][2] += a2*b.z; S[2][3] += a2*b.w;
          S[3][0] += a3*b.x; S[3][1] += a3*b.y; S[3][2] += a3*b.z; S[3][3] += a3*b.w;
        }
      }
    }
    // ---- online softmax: row = wave (lane tx owns keys tx*4..+3) ----
    float pp[4][4];
    #pragma unroll
    for (int r = 0; r < 4; ++r){
      #pragma unroll
      for (int e = 0; e < 4; ++e) S[r][e] *= QK_SCALE;
      float tm = fmaxf(fmaxf(S[r][0], S[r][1]), fmaxf(S[r][2], S[r][3]));
      tm = fmaxf(tm, __shfl_xor(tm, 1));
      tm = fmaxf(tm, __shfl_xor(tm, 2));
      tm = fmaxf(tm, __shfl_xor(tm, 4));
      tm = fmaxf(tm, __shfl_xor(tm, 8));
      tm = fmaxf(tm, __shfl_xor(tm, 16));
      tm = fmaxf(tm, __shfl_xor(tm, 32));
      const float mn = fmaxf(mr[r], tm);
      const float al = expf(mr[r] - mn);
      pp[r][0] = expf(S[r][0] - mn); pp[r][1] = expf(S[r][1] - mn);
      pp[r][2] = expf(S[r][2] - mn); pp[r][3] = expf(S[r][3] - mn);
      float rs = (pp[r][0] + pp[r][1]) + (pp[r][2] + pp[r][3]);
      rs += __shfl_xor(rs, 1); rs += __shfl_xor(rs, 2);
      rs += __shfl_xor(rs, 4); rs += __shfl_xor(rs, 8);
      rs += __shfl_xor(rs, 16); rs += __shfl_xor(rs, 32);
      lr[r] = lr[r]*al + rs;
      mr[r] = mn;
      O[r][0] *= al; O[r][1] *= al; O[r][2] *= al; O[r][3] *= al;
    }
    // ---- PV over 16 chunks of 16 keys; P via readlane ----
    for (int ks = 0; ks < 16; ++ks){
      __syncthreads();                          // prev chunk readers done
      #pragma unroll
      for (int i = 0; i < 2; ++i){              // stage V chunk natural
        const int c = i*512 + tid;
        const int key = c >> 6, d4 = c & 63;
        *(f32x4*)&KV[key*260 + d4*4] =
            *(const f32x4*)&QKV[(size_t)(kb + ks*16 + key)*768 + 512 + d4*4];
      }
      __syncthreads();
      #pragma unroll
      for (int kg = 0; kg < 4; ++kg){
        const int ln = ks*4 + kg;               // lane owning these 4 keys
        #pragma unroll
        for (int k2 = 0; k2 < 4; ++k2){
          const float a0 = rdl(pp[0][k2], ln);
          const float a1 = rdl(pp[1][k2], ln);
          const float a2 = rdl(pp[2][k2], ln);
          const float a3 = rdl(pp[3][k2], ln);
          const f32x4 v = *(const f32x4*)&KV[(kg*4+k2)*260 + tx*4];
          O[0][0] += a0*v.x; O[0][1] += a0*v.y; O[0][2] += a0*v.z; O[0][3] += a0*v.w;
          O[1][0] += a1*v.x; O[1][1] += a1*v.y; O[1][2] += a1*v.z; O[1][3] += a1*v.w;
          O[2][0] += a2*v.x; O[2][1] += a2*v.y; O[2][2] += a2*v.z; O[2][3] += a2*v.w;
          O[3][0] += a3*v.x; O[3][1] += a3*v.y; O[3][2] += a3*v.z; O[3][3] += a3*v.w;
        }
      }
    }
  }
  // ---- epilogue: normalize + fused gate + memory/pointer update ----
  const float bc0 = bc[0], bc1 = bc[1], bc2 = bc[2];
  #pragma unroll
  for (int r = 0; r < 4; ++r){
    const float inv = 1.f / lr[r];
    #pragma unroll
    for (int j = 0; j < 4; ++j) O[r][j] *= inv;
    float d0 = 0.f, d1 = 0.f, d2 = 0.f;
    #pragma unroll
    for (int j = 0; j < 4; ++j){
      const int dim = tx*4 + j;
      const float z = O[r][j];
      d0 += z*Wc[dim*3 + 0]; d1 += z*Wc[dim*3 + 1]; d2 += z*Wc[dim*3 + 2];
    }
    d0 += __shfl_xor(d0,1); d0 += __shfl_xor(d0,2); d0 += __shfl_xor(d0,4);
    d0 += __shfl_xor(d0,8); d0 += __shfl_xor(d0,16); d0 += __shfl_xor(d0,32);
    d1 += __shfl_xor(d1,1); d1 += __shfl_xor(d1,2); d1 += __shfl_xor(d1,4);
    d1 += __shfl_xor(d1,8); d1 += __shfl_xor(d1,16); d1 += __shfl_xor(d1,32);
    d2 += __shfl_xor(d2,1); d2 += __shfl_xor(d2,2); d2 += __shfl_xor(d2,4);
    d2 += __shfl_xor(d2,8); d2 += __shfl_xor(d2,16); d2 += __shfl_xor(d2,32);
    const float g0 = 1.f/(1.f + expf(-(d0 + bc0)));
    const float g1 = 1.f/(1.f + expf(-(d1 + bc1)));
    const float g2 = 1.f/(1.f + expf(-(d2 + bc2)));
    const float tt = g0 + g1 + g2, tot = tt + 1e-6f;
    const float push = g0/tot;
    const int row = nbase + ty*4 + r;
    if (tx == 0) PSUM[row] *= tt/tot;
    const size_t idx = (size_t)row*256 + tx*4;
    f32x4 z0 = {O[r][0], O[r][1], O[r][2], O[r][3]};
    f32x4 m0 = *(const f32x4*)&Mm[idx];
    m0.x += push*(z0.x - m0.x); m0.y += push*(z0.y - m0.y);
    m0.z += push*(z0.z - m0.z); m0.w += push*(z0.w - m0.w);
    *(f32x4*)&Mm[idx] = m0;
    *(f32x4*)&ZF[idx] = z0;
  }
}

// ---------------------------------------------------------------------------
extern "C" void kernel_launch(void* const* d_in, const int* in_sizes, int n_in,
                              void* d_out, int out_size, void* d_ws, size_t ws_size,
                              hipStream_t stream){
  (void)in_sizes; (void)n_in; (void)out_size; (void)ws_size;
  const float* xr   = (const float*)d_in[0];
  const float* xi   = (const float*)d_in[1];
  const float* Wq_r = (const float*)d_in[2];
  const float* Wq_i = (const float*)d_in[3];
  const float* Wk_r = (const float*)d_in[4];
  const float* Wk_i = (const float*)d_in[5];
  const float* Wv_r = (const float*)d_in[6];
  const float* Wv_i = (const float*)d_in[7];
  // d_in[8..11] (Mq_*, Mk_*) unused: all stack slots identical -> memory
  // attention exactly uniform regardless of its q/k projections (verified r3).
  const float* Mv_r = (const float*)d_in[12];
  const float* Mv_i = (const float*)d_in[13];
  const float* Wc   = (const float*)d_in[14];
  const float* bc   = (const float*)d_in[15];
  const float* Wo   = (const float*)d_in[16];
  const float* bo   = (const float*)d_in[17];

  // Workspace layout identical to verified round 3/6 (41,975,808 B).
  uint8_t* w = (uint8_t*)d_ws;
  float* Z    = (float*)w; w += (size_t)8192*256*4;   // state; aliased as ZF
  float* QKV  = (float*)w; w += (size_t)8192*768*4;
  float* Mm   = (float*)w; w += (size_t)8192*256*4;
  float* PSUM = (float*)w; w += (size_t)8192*4;
  float* ZF   = Z;  // safe alias: state dead once proj consumed it.

  k_init32<<<dim3(1024), dim3(256), 0, stream>>>(xr, xi, Z, Mm, PSUM);
  for (int t = 0; t < 8; ++t){
    k_gemm32<0,64><<<dim3(768), dim3(256), 0, stream>>>(Z, 6,
        Wq_r, Wq_i, Wk_r, Wk_i, Wv_r, Wv_i, QKV, nullptr, nullptr);
    k_attn32<<<dim3(256), dim3(512), 0, stream>>>(QKV, ZF, Mm, PSUM, Wc, bc);
    k_gemm32<1,64><<<dim3(256), dim3(256), 0, stream>>>(Mm, 2,
        Mv_r, Mv_i, nullptr, nullptr, nullptr, nullptr, Z, PSUM, nullptr);
  }
  k_gemm32<2,128><<<dim3(64), dim3(256), 0, stream>>>(Z, 1,
      Wo, nullptr, nullptr, nullptr, nullptr, nullptr, (float*)d_out, nullptr, bo);
}